// Round 10
// baseline (265.710 us; speedup 1.0000x reference)
//
#include <hip/hip_runtime.h>

typedef unsigned short u16;
typedef __attribute__((ext_vector_type(8))) short bf16x8;
typedef __attribute__((ext_vector_type(4))) short s16x4;
typedef __attribute__((ext_vector_type(4))) float f32x4;

#define MFMA(a, b, c) __builtin_amdgcn_mfma_f32_16x16x32_bf16(a, b, c, 0, 0, 0)

// global -> LDS direct copy, 16 B per lane. LDS dest must be wave-uniform base
// (HW adds lane*16). Global source is per-lane.
#define GLDS16(gp, lp)                                                        \
  __builtin_amdgcn_global_load_lds(                                          \
      (__attribute__((address_space(1))) void*)(void*)(gp),                  \
      (__attribute__((address_space(3))) void*)(lp), 16, 0, 0)

__device__ __forceinline__ u16 f2b(float f) {
  union { float f; unsigned u; } x; x.f = f;
  unsigned r = x.u + 0x7fffu + ((x.u >> 16) & 1u);
  return (u16)(r >> 16);
}

// Stage a [32*NPASS rows][64 cols] bf16 tile into LDS with XOR-swizzled SOURCE
// slots so a swizzled ds_read recovers linear data. (256-thread version.)
template <int NPASS>
__device__ __forceinline__ void stage64(const u16* __restrict__ src, int ld,
                                        u16* lds, int t) {
  int wave = t >> 6;
#pragma unroll
  for (int p = 0; p < NPASS; ++p) {
    int row = p * 32 + (t >> 3);
    int ss = (t & 7) ^ (row & 7);
    const u16* g = src + row * ld + ss * 8;
    GLDS16(g, lds + (p * 2048 + wave * 512));
  }
}

// read one MFMA fragment (8 consecutive bf16) at [row][slot*8], swizzle-corrected
__device__ __forceinline__ bf16x8 ldsfrag(const u16* base, int row, int slot) {
  int byte = row * 128 + (((slot) ^ (row & 7)) << 4);
  return *(const bf16x8*)((const char*)base + byte);
}

// ---------------------------------------------------------------- prep kernels
__global__ void cast_x_kernel(const float* __restrict__ in, u16* __restrict__ out,
                              int n4) {
  int i = blockIdx.x * blockDim.x + threadIdx.x;
  if (i < n4) {
    float4 v = ((const float4*)in)[i];
    ushort4 o;
    o.x = f2b(v.x); o.y = f2b(v.y); o.z = f2b(v.z); o.w = f2b(v.w);
    ((ushort4*)out)[i] = o;
  }
}

// out[(c, r)] = bf16(in[(r, c)]); in is (R, Ccols) fp32 row-major.
__global__ void transpose_cast(const float* __restrict__ in, u16* __restrict__ out,
                               int R, int Ccols) {
  __shared__ u16 tile[32][33];
  int c0 = blockIdx.x * 32, r0 = blockIdx.y * 32;
  int tx = threadIdx.x & 31, ty = threadIdx.x >> 5;
#pragma unroll
  for (int rr = ty; rr < 32; rr += 8)
    tile[rr][tx] = f2b(in[(size_t)(r0 + rr) * Ccols + c0 + tx]);
  __syncthreads();
#pragma unroll
  for (int rr = ty; rr < 32; rr += 8)
    out[(size_t)(c0 + rr) * R + r0 + tx] = tile[tx][rr];
}

// bias_table (65025,12) fp32 -> per-head contiguous f32 [12][4096] (3969 used)
// PRE-SCALED by log2(e): softmax runs in exp2 domain.
__global__ void gather_bias(const float* __restrict__ btab, float* __restrict__ out) {
  int i = blockIdx.x * 256 + threadIdx.x;  // [0, 12*4096)
  int h = i >> 12, r = i & 4095;
  out[i] = (r < 3969) ? btab[r * 12 + h] * 1.44269504f : 0.f;
}

// ---------------------------------------------------------------- GEMM 128x128
// C = A(M,K) @ BT(N,K)^T, bf16 inputs, fp32 accum.
template <int EPI>
__global__ __launch_bounds__(256, 2) void gemm128(
    const u16* __restrict__ A, const u16* __restrict__ BT, int K,
    u16* __restrict__ qo, u16* __restrict__ ko, u16* __restrict__ vo,
    const float* __restrict__ pb, float* __restrict__ out, int Nld) {
  __shared__ __align__(16) u16 As[128 * 64];
  __shared__ __align__(16) u16 Bs[128 * 64];
  const int t = threadIdx.x;
  const int wave = t >> 6, lane = t & 63;
  const int wr = wave >> 1, wc = wave & 1;
  const int tileRow = blockIdx.y * 128, tileCol = blockIdx.x * 128;
  const u16* Ab = A + (size_t)tileRow * K;
  const u16* Bb = BT + (size_t)tileCol * K;

  f32x4 acc[4][4] = {};
  for (int k0 = 0; k0 < K; k0 += 64) {
    __syncthreads();
    stage64<4>(Ab + k0, K, As, t);
    stage64<4>(Bb + k0, K, Bs, t);
    __syncthreads();
#pragma unroll
    for (int kk = 0; kk < 2; ++kk) {
      bf16x8 af[4], bfr[4];
#pragma unroll
      for (int m = 0; m < 4; ++m)
        af[m] = ldsfrag(As, wr * 64 + m * 16 + (lane & 15), kk * 4 + (lane >> 4));
#pragma unroll
      for (int n = 0; n < 4; ++n)
        bfr[n] = ldsfrag(Bs, wc * 64 + n * 16 + (lane & 15), kk * 4 + (lane >> 4));
#pragma unroll
      for (int m = 0; m < 4; ++m)
#pragma unroll
        for (int n = 0; n < 4; ++n)
          acc[m][n] = MFMA(af[m], bfr[n], acc[m][n]);
    }
  }

#pragma unroll
  for (int m = 0; m < 4; ++m) {
#pragma unroll
    for (int n = 0; n < 4; ++n) {
#pragma unroll
      for (int r = 0; r < 4; ++r) {
        int row = tileRow + wr * 64 + m * 16 + (lane >> 4) * 4 + r;
        int col = tileCol + wc * 64 + n * 16 + (lane & 15);
        float val = acc[m][n][r];
        if (EPI == 0) {
          int which = col / 768;
          int c = col - which * 768;
          int hh = c >> 6, d = c & 63;
          int bb = row >> 10, nn = row & 1023;
          size_t bhnd = ((size_t)(bb * 12 + hh) * 1024 + nn) * 64 + d;
          if (which == 0)
            qo[bhnd] = f2b(val * 0.18033688f);  // 0.125 * log2(e)
          else if (which == 1)
            ko[bhnd] = f2b(val);
          else
            vo[((size_t)(bb * 12 + hh) * 64 + d) * 1024 + nn] = f2b(val);
        } else {
          out[(size_t)row * Nld + col] = val + pb[col];
        }
      }
    }
  }
}

// ---------------------------------------------------------------- attention
// Barrier-free main loop: K/V MFMA fragments loaded global->REGISTER with
// rolling prefetch (K double-buffered ka/kb via manual 2x unroll; V single-set
// issued right after its PV consumer). LDS holds only the f32 bias slice
// (read-only after one prologue sync) and wave-local P tiles. This removes
// the LDS-BW ceiling (was ~23KB/wave-iter) and all per-iter barriers.
// grid: 1536 flat (XCD-chunked: one batch per XCD); block: 256 (4 waves).
__global__ __launch_bounds__(256, 3) void attn_kernel(
    const u16* __restrict__ qm, const u16* __restrict__ kmat,
    const u16* __restrict__ vT, const float* __restrict__ bias_g,
    u16* __restrict__ ao) {
  __shared__ __align__(16) float bias_sf[33 * 64];  // 8448 B
  __shared__ __align__(16) u16 Ps[4][1024];         // per-wave 16x64 P tile

  const int t = threadIdx.x;
  const int wave = t >> 6, lane = t & 63;
  const int g = lane >> 4, q = lane & 15;
  // XCD-chunked swizzle: id%8 = XCD, one batch (192 blocks) per XCD.
  const int id = blockIdx.x;
  const int sw = (id & 7) * 192 + (id >> 3);
  const int qt = sw & 15, h = (sw >> 4) % 12, b = sw / 192;
  const int bh = b * 12 + h;

  const u16* kb0 = kmat + (size_t)bh * 1024 * 64;
  const u16* vb0 = vT + (size_t)bh * 64 * 1024;

  // prologue: stage f32 bias rows dy in [2qt, 2qt+32], 63 cols, stride-64 pad
  {
    const float* bg = bias_g + h * 4096 + qt * 2 * 63;
#pragma unroll
    for (int p = 0; p < 2; ++p)
      GLDS16(bg + (p * 16 + (t >> 4)) * 63 + (t & 15) * 4,
             (char*)bias_sf + p * 4096 + (t >> 6) * 1024);
    if (t < 16)
      GLDS16(bg + (32 + (t >> 4)) * 63 + (t & 15) * 4, (char*)bias_sf + 8192);
  }

  // Q fragments in registers (q pre-scaled by 0.125*log2e); B-operand: col = q
  const u16* qb = qm + ((size_t)bh * 1024 + qt * 64) * 64;
  bf16x8 qf[2];
#pragma unroll
  for (int kk = 0; kk < 2; ++kk)
    qf[kk] = *(const bf16x8*)(qb + (wave * 16 + q) * 64 + kk * 32 + g * 8);

  f32x4 o[4] = {};
  float mrun = -1e30f, lrun = 0.f;

  // this lane's softmax q-row (for S^T layout)
  const int iq = qt * 64 + wave * 16 + q;
  const int ylq = (wave * 16 + q) >> 5;  // local yi (0 or 1)
  const int xi = iq & 31;

  auto loadK = [&](bf16x8 (&kf)[8], int kt) {
#pragma unroll
    for (int kk = 0; kk < 2; ++kk)
#pragma unroll
      for (int n = 0; n < 4; ++n)
        kf[kk * 4 + n] = *(const bf16x8*)(
            kb0 + ((size_t)kt * 64 + n * 16 + q) * 64 + kk * 32 + g * 8);
  };
  auto loadV = [&](bf16x8 (&vf)[8], int kt) {
#pragma unroll
    for (int kk = 0; kk < 2; ++kk)
#pragma unroll
      for (int nd = 0; nd < 4; ++nd)
        vf[kk * 4 + nd] = *(const bf16x8*)(
            vb0 + (size_t)(nd * 16 + q) * 1024 + kt * 64 + kk * 32 + g * 8);
  };

  auto compute = [&](bf16x8 (&kf)[8], bf16x8 (&vf)[8], int kt) {
    // S^T = K @ Q^T: s[n][r] = S[key = n*16 + g*4 + r][qrow = q]
    f32x4 s[4] = {};
#pragma unroll
    for (int kk = 0; kk < 2; ++kk)
#pragma unroll
      for (int n = 0; n < 4; ++n)
        s[n] = MFMA(kf[kk * 4 + n], qf[kk], s[n]);

    // + relative position bias (f32 LDS, exp2-domain)
#pragma unroll
    for (int n = 0; n < 4; ++n) {
      int xj0 = (n & 1) * 16 + g * 4;
      int ldy = ylq - kt * 2 - (n >> 1) + 31;
      int bse = ldy * 64 + (xi - xj0 + 31);
#pragma unroll
      for (int r = 0; r < 4; ++r) s[n][r] += bias_sf[bse - r];
    }

    // row max: 15 local fmax + 2 cross-group shuffles
    float mx = fmaxf(fmaxf(fmaxf(s[0][0], s[0][1]), fmaxf(s[0][2], s[0][3])),
                     fmaxf(fmaxf(s[1][0], s[1][1]), fmaxf(s[1][2], s[1][3])));
    mx = fmaxf(mx,
               fmaxf(fmaxf(fmaxf(s[2][0], s[2][1]), fmaxf(s[2][2], s[2][3])),
                     fmaxf(fmaxf(s[3][0], s[3][1]), fmaxf(s[3][2], s[3][3]))));
    mx = fmaxf(mx, __shfl_xor(mx, 16));
    mx = fmaxf(mx, __shfl_xor(mx, 32));

    // defer-max (8 nats = 11.54 bits; exp2 domain)
    if (__any(mx > mrun + 11.5f)) {
      float mn = fmaxf(mrun, mx);
      float al = __builtin_amdgcn_exp2f(mrun - mn);
      mrun = mn;
      lrun *= al;
#pragma unroll
      for (int r = 0; r < 4; ++r) {
        float ar = __shfl(al, (lane & 48) | (g * 4 + r));
#pragma unroll
        for (int nd = 0; nd < 4; ++nd) o[nd][r] *= ar;
      }
    }

    // exp2 + sum
    float ps = 0.f;
#pragma unroll
    for (int n = 0; n < 4; ++n)
#pragma unroll
      for (int r = 0; r < 4; ++r) {
        float p = __builtin_amdgcn_exp2f(s[n][r] - mrun);
        s[n][r] = p;
        ps += p;
      }
    ps += __shfl_xor(ps, 16);
    ps += __shfl_xor(ps, 32);
    lrun += ps;

    // P -> wave-local LDS (row q, keys n*16+g*4..+3), swizzled, short4 stores
#pragma unroll
    for (int n = 0; n < 4; ++n) {
      int byte = (q * 128 + n * 32 + g * 8) ^ ((q & 7) << 4);
      union { unsigned u[2]; s16x4 v; } w;
      w.u[0] = (unsigned)f2b(s[n][0]) | ((unsigned)f2b(s[n][1]) << 16);
      w.u[1] = (unsigned)f2b(s[n][2]) | ((unsigned)f2b(s[n][3]) << 16);
      *(s16x4*)((char*)Ps[wave] + byte) = w.v;
    }
    __builtin_amdgcn_sched_barrier(0);  // fence: P stores before PV reads

    // O += P @ V (A-frag: row q; V^T frags in registers)
#pragma unroll
    for (int kk = 0; kk < 2; ++kk) {
      bf16x8 pf = ldsfrag(Ps[wave], q, kk * 4 + g);
#pragma unroll
      for (int nd = 0; nd < 4; ++nd)
        o[nd] = MFMA(pf, vf[kk * 4 + nd], o[nd]);
    }
  };

  bf16x8 ka[8], kb[8], v[8];
  loadK(ka, 0);
  loadV(v, 0);

  __syncthreads();  // bias landed (only block-wide barrier in the kernel)

  for (int kt2 = 0; kt2 < 8; ++kt2) {
    loadK(kb, 2 * kt2 + 1);          // in flight during compute(ka)
    compute(ka, v, 2 * kt2);
    loadV(v, 2 * kt2 + 1);           // lands during next QK+softmax
    if (kt2 < 7) loadK(ka, 2 * kt2 + 2);
    compute(kb, v, 2 * kt2 + 1);
    if (kt2 < 7) loadV(v, 2 * kt2 + 2);
  }

  // epilogue: redistribute 1/l to output rows, O/l -> (B, N, nh*hd) bf16
  float lr[4];
#pragma unroll
  for (int r = 0; r < 4; ++r)
    lr[r] = __shfl(lrun, (lane & 48) | (g * 4 + r));
#pragma unroll
  for (int nd = 0; nd < 4; ++nd) {
#pragma unroll
    for (int r = 0; r < 4; ++r) {
      int i = qt * 64 + wave * 16 + g * 4 + r;
      int d = nd * 16 + q;
      float val = o[nd][r] / lr[r];
      ao[((size_t)b * 1024 + i) * 768 + h * 64 + d] = f2b(val);
    }
  }
}

// ---------------------------------------------------------------- launcher
extern "C" void kernel_launch(void* const* d_in, const int* in_sizes, int n_in,
                              void* d_out, int out_size, void* d_ws, size_t ws_size,
                              hipStream_t stream) {
  const float* x = (const float*)d_in[0];
  const float* qkvw = (const float*)d_in[1];
  const float* projw = (const float*)d_in[2];
  const float* projb = (const float*)d_in[3];
  const float* btab = (const float*)d_in[4];
  float* out = (float*)d_out;
  char* ws = (char*)d_ws;

  // workspace layout (bytes)
  u16* xb = (u16*)(ws);                    // 8192*768 bf16 = 12,582,912 B
  u16* wqkvT = (u16*)(ws + 12582912);      // 2304*768 bf16 =  3,538,944 B
  u16* wprojT = (u16*)(ws + 16121856);     //  768*768 bf16 =  1,179,648 B
  u16* qbuf = (u16*)(ws + 17301504);       // 12,582,912 B
  u16* kbuf = (u16*)(ws + 29884416);       // 12,582,912 B
  u16* vTbuf = (u16*)(ws + 42467328);      // 12,582,912 B
  float* biasg = (float*)(ws + 55050240);  // 12*4096*4 =     196,608 B
  u16* ao = xb;  // reuse: xb dead after QKV GEMM (stream-serialized)

  cast_x_kernel<<<6144, 256, 0, stream>>>(x, xb, 8192 * 768 / 4);
  transpose_cast<<<dim3(72, 24), 256, 0, stream>>>(qkvw, wqkvT, 768, 2304);
  transpose_cast<<<dim3(24, 24), 256, 0, stream>>>(projw, wprojT, 768, 768);
  gather_bias<<<192, 256, 0, stream>>>(btab, biasg);

  gemm128<0><<<dim3(18, 64), 256, 0, stream>>>(xb, wqkvT, 768, qbuf, kbuf,
                                               vTbuf, nullptr, nullptr, 0);

  attn_kernel<<<1536, 256, 0, stream>>>(qbuf, kbuf, vTbuf, biasg, ao);

  gemm128<1><<<dim3(6, 64), 256, 0, stream>>>(ao, wprojT, 768, nullptr, nullptr,
                                              nullptr, projb, out, 768);
}

// Round 11
// 173.832 us; speedup vs baseline: 1.5285x; 1.5285x over previous
//
#include <hip/hip_runtime.h>

typedef unsigned short u16;
typedef __attribute__((ext_vector_type(8))) short bf16x8;
typedef __attribute__((ext_vector_type(4))) short s16x4;
typedef __attribute__((ext_vector_type(4))) float f32x4;

#define MFMA(a, b, c) __builtin_amdgcn_mfma_f32_16x16x32_bf16(a, b, c, 0, 0, 0)

// global -> LDS direct copy, 16 B per lane. LDS dest must be wave-uniform base
// (HW adds lane*16). Global source is per-lane.
#define GLDS16(gp, lp)                                                        \
  __builtin_amdgcn_global_load_lds(                                          \
      (__attribute__((address_space(1))) void*)(void*)(gp),                  \
      (__attribute__((address_space(3))) void*)(lp), 16, 0, 0)

__device__ __forceinline__ u16 f2b(float f) {
  union { float f; unsigned u; } x; x.f = f;
  unsigned r = x.u + 0x7fffu + ((x.u >> 16) & 1u);
  return (u16)(r >> 16);
}
__device__ __forceinline__ float b2f(u16 v) {
  union { unsigned u; float f; } x; x.u = ((unsigned)v) << 16;
  return x.f;
}

// Stage a [32*NPASS rows][64 cols] bf16 tile into LDS with XOR-swizzled SOURCE
// slots so a swizzled ds_read recovers linear data. (256-thread version.)
template <int NPASS>
__device__ __forceinline__ void stage64(const u16* __restrict__ src, int ld,
                                        u16* lds, int t) {
  int wave = t >> 6;
#pragma unroll
  for (int p = 0; p < NPASS; ++p) {
    int row = p * 32 + (t >> 3);
    int ss = (t & 7) ^ (row & 7);
    const u16* g = src + row * ld + ss * 8;
    GLDS16(g, lds + (p * 2048 + wave * 512));
  }
}

// 512-thread version: one pass stages a full 64x64 bf16 tile.
__device__ __forceinline__ void stage512(const u16* __restrict__ src, int ld,
                                         u16* lds, int t) {
  int row = t >> 3;
  int ss = (t & 7) ^ (row & 7);
  GLDS16(src + row * ld + ss * 8, lds + (t >> 6) * 512);
}

// read one MFMA fragment (8 consecutive bf16) at [row][slot*8], swizzle-corrected
__device__ __forceinline__ bf16x8 ldsfrag(const u16* base, int row, int slot) {
  int byte = row * 128 + (((slot) ^ (row & 7)) << 4);
  return *(const bf16x8*)((const char*)base + byte);
}

// ---------------------------------------------------------------- prep kernels
__global__ void cast_x_kernel(const float* __restrict__ in, u16* __restrict__ out,
                              int n4) {
  int i = blockIdx.x * blockDim.x + threadIdx.x;
  if (i < n4) {
    float4 v = ((const float4*)in)[i];
    ushort4 o;
    o.x = f2b(v.x); o.y = f2b(v.y); o.z = f2b(v.z); o.w = f2b(v.w);
    ((ushort4*)out)[i] = o;
  }
}

// out[(c, r)] = bf16(in[(r, c)]); in is (R, Ccols) fp32 row-major.
__global__ void transpose_cast(const float* __restrict__ in, u16* __restrict__ out,
                               int R, int Ccols) {
  __shared__ u16 tile[32][33];
  int c0 = blockIdx.x * 32, r0 = blockIdx.y * 32;
  int tx = threadIdx.x & 31, ty = threadIdx.x >> 5;
#pragma unroll
  for (int rr = ty; rr < 32; rr += 8)
    tile[rr][tx] = f2b(in[(size_t)(r0 + rr) * Ccols + c0 + tx]);
  __syncthreads();
#pragma unroll
  for (int rr = ty; rr < 32; rr += 8)
    out[(size_t)(c0 + rr) * R + r0 + tx] = tile[tx][rr];
}

// bias_table (65025,12) fp32 -> per-head contiguous bf16 [12][4096] (3969 used)
// PRE-SCALED by log2(e): softmax runs in exp2 domain.
__global__ void gather_bias(const float* __restrict__ btab, u16* __restrict__ out) {
  int i = blockIdx.x * 256 + threadIdx.x;  // [0, 12*4096)
  int h = i >> 12, r = i & 4095;
  out[i] = (r < 3969) ? f2b(btab[r * 12 + h] * 1.44269504f) : (u16)0;
}

// ---------------------------------------------------------------- GEMM 128x128
// C = A(M,K) @ BT(N,K)^T, bf16 inputs, fp32 accum.
template <int EPI>
__global__ __launch_bounds__(256, 3) void gemm128(
    const u16* __restrict__ A, const u16* __restrict__ BT, int K,
    u16* __restrict__ qo, u16* __restrict__ ko, u16* __restrict__ vo,
    const float* __restrict__ pb, float* __restrict__ out, int Nld) {
  __shared__ __align__(16) u16 As[128 * 64];
  __shared__ __align__(16) u16 Bs[128 * 64];
  const int t = threadIdx.x;
  const int wave = t >> 6, lane = t & 63;
  const int wr = wave >> 1, wc = wave & 1;
  const int tileRow = blockIdx.y * 128, tileCol = blockIdx.x * 128;
  const u16* Ab = A + (size_t)tileRow * K;
  const u16* Bb = BT + (size_t)tileCol * K;

  f32x4 acc[4][4] = {};
  for (int k0 = 0; k0 < K; k0 += 64) {
    __syncthreads();
    stage64<4>(Ab + k0, K, As, t);
    stage64<4>(Bb + k0, K, Bs, t);
    __syncthreads();
#pragma unroll
    for (int kk = 0; kk < 2; ++kk) {
      bf16x8 af[4], bfr[4];
#pragma unroll
      for (int m = 0; m < 4; ++m)
        af[m] = ldsfrag(As, wr * 64 + m * 16 + (lane & 15), kk * 4 + (lane >> 4));
#pragma unroll
      for (int n = 0; n < 4; ++n)
        bfr[n] = ldsfrag(Bs, wc * 64 + n * 16 + (lane & 15), kk * 4 + (lane >> 4));
#pragma unroll
      for (int m = 0; m < 4; ++m)
#pragma unroll
        for (int n = 0; n < 4; ++n)
          acc[m][n] = MFMA(af[m], bfr[n], acc[m][n]);
    }
  }

#pragma unroll
  for (int m = 0; m < 4; ++m) {
#pragma unroll
    for (int n = 0; n < 4; ++n) {
#pragma unroll
      for (int r = 0; r < 4; ++r) {
        int row = tileRow + wr * 64 + m * 16 + (lane >> 4) * 4 + r;
        int col = tileCol + wc * 64 + n * 16 + (lane & 15);
        float val = acc[m][n][r];
        if (EPI == 0) {
          int which = col / 768;
          int c = col - which * 768;
          int hh = c >> 6, d = c & 63;
          int bb = row >> 10, nn = row & 1023;
          size_t bhnd = ((size_t)(bb * 12 + hh) * 1024 + nn) * 64 + d;
          if (which == 0)
            qo[bhnd] = f2b(val * 0.18033688f);  // 0.125 * log2(e)
          else if (which == 1)
            ko[bhnd] = f2b(val);
          else
            vo[((size_t)(bb * 12 + hh) * 64 + d) * 1024 + nn] = f2b(val);
        } else {
          out[(size_t)row * Nld + col] = val + pb[col];
        }
      }
    }
  }
}

// ---------------------------------------------------------------- attention
// R9 structure (8-wave blocks, QBLK=128, KVBLK=128 LDS-staged, swapped-QK,
// exp2 domain) with ONE softmax pass per 128 keys: single max-reduce (31
// local fmax + 2 shfl), single defer-max check, single sum-reduce, single
// rescale. P tile is 16x128 per wave (row stride 256B, same XOR swizzle).
// grid: 768 flat (XCD-chunked: one batch per XCD); block: 512 (8 waves).
__global__ __launch_bounds__(512, 4) void attn_kernel(
    const u16* __restrict__ qm, const u16* __restrict__ kmat,
    const u16* __restrict__ vT, const u16* __restrict__ bias_g,
    u16* __restrict__ ao) {
  __shared__ __align__(16) u16 bias_s[35 * 64];
  __shared__ __align__(16) u16 Ks[2][64 * 64];
  __shared__ __align__(16) u16 Vs[2][64 * 64];
  __shared__ __align__(16) u16 Ps[8][2048];  // per-wave 16x128 P tile

  const int t = threadIdx.x;
  const int wave = t >> 6, lane = t & 63;
  const int g = lane >> 4, q = lane & 15;
  // XCD-chunked swizzle: id%8 = XCD, one batch (96 blocks) per XCD.
  const int id = blockIdx.x;
  const int sw = (id & 7) * 96 + (id >> 3);
  const int qt = sw & 7, h = (sw >> 3) % 12, b = sw / 96;
  const int bh = b * 12 + h;

  const u16* kb0 = kmat + (size_t)bh * 1024 * 64;
  const u16* vb0 = vT + (size_t)bh * 64 * 1024;

  // prologue: bias rows dy in [4qt, 4qt+34] (63 cols, stride-64 pad)
  if (t < 280) {
    const u16* bg = bias_g + h * 4096 + qt * 4 * 63;
    GLDS16(bg + (t >> 3) * 63 + (t & 7) * 8, bias_s + (t >> 6) * 512);
  }

  // Q fragments in registers (q pre-scaled by 0.125*log2e); B-operand: col = q
  const u16* qb = qm + ((size_t)bh * 1024 + qt * 128) * 64;
  bf16x8 qf[2];
#pragma unroll
  for (int kk = 0; kk < 2; ++kk)
    qf[kk] = *(const bf16x8*)(qb + (wave * 16 + q) * 64 + kk * 32 + g * 8);

  f32x4 o[4] = {};
  float mrun = -1e30f, lrun = 0.f;

  // this lane's softmax q-row (for S^T layout)
  const int iq = qt * 128 + wave * 16 + q;
  const int ylq = (wave * 16 + q) >> 5;  // local yi (0..3): yi = 4qt + ylq
  const int xi = iq & 31;

  for (int kt8 = 0; kt8 < 8; ++kt8) {
    __syncthreads();  // all waves done reading K/V (prev round)
    stage512(kb0 + kt8 * 8192, 64, Ks[0], t);
    stage512(kb0 + kt8 * 8192 + 4096, 64, Ks[1], t);
    stage512(vb0 + kt8 * 128, 1024, Vs[0], t);
    stage512(vb0 + kt8 * 128 + 64, 1024, Vs[1], t);
    __syncthreads();  // 128-key tile landed

    // S^T = K @ Q^T over 128 keys: s[half*4+n][r] = S[key][qrow = q],
    // key = half*64 + n*16 + g*4 + r
    f32x4 s[8] = {};
#pragma unroll
    for (int half = 0; half < 2; ++half)
#pragma unroll
      for (int kk = 0; kk < 2; ++kk)
#pragma unroll
        for (int n = 0; n < 4; ++n)
          s[half * 4 + n] =
              MFMA(ldsfrag(Ks[half], n * 16 + q, kk * 4 + g), qf[kk],
                   s[half * 4 + n]);

    // + relative position bias (exp2-domain)
#pragma unroll
    for (int half = 0; half < 2; ++half) {
      const int kt = kt8 * 2 + half;
#pragma unroll
      for (int n = 0; n < 4; ++n) {
        int xj0 = (n & 1) * 16 + g * 4;
        int ldy = ylq - kt * 2 - (n >> 1) + 31;
        int bse = ldy * 64 + (xi - xj0 + 31);
#pragma unroll
        for (int r = 0; r < 4; ++r) s[half * 4 + n][r] += b2f(bias_s[bse - r]);
      }
    }

    // row max over 128 keys: 31 local fmax + 2 cross-group shuffles
    float mx = -1e30f;
#pragma unroll
    for (int i = 0; i < 8; ++i)
#pragma unroll
      for (int r = 0; r < 4; ++r) mx = fmaxf(mx, s[i][r]);
    mx = fmaxf(mx, __shfl_xor(mx, 16));
    mx = fmaxf(mx, __shfl_xor(mx, 32));

    // defer-max (8 nats = 11.54 bits; exp2 domain) -- once per 128 keys
    if (__any(mx > mrun + 11.5f)) {
      float mn = fmaxf(mrun, mx);
      float al = __builtin_amdgcn_exp2f(mrun - mn);
      mrun = mn;
      lrun *= al;
#pragma unroll
      for (int r = 0; r < 4; ++r) {
        float ar = __shfl(al, (lane & 48) | (g * 4 + r));
#pragma unroll
        for (int nd = 0; nd < 4; ++nd) o[nd][r] *= ar;
      }
    }

    // exp2 + sum (single pass over 32 values)
    float ps = 0.f;
#pragma unroll
    for (int i = 0; i < 8; ++i)
#pragma unroll
      for (int r = 0; r < 4; ++r) {
        float p = __builtin_amdgcn_exp2f(s[i][r] - mrun);
        s[i][r] = p;
        ps += p;
      }
    ps += __shfl_xor(ps, 16);
    ps += __shfl_xor(ps, 32);
    lrun += ps;

    // P -> wave-local LDS, 16x128 tile, row q at stride 256B, swizzled b64
    // key j -> byte q*256 + j*2; i = half*4+n covers keys i*16+g*4+r
#pragma unroll
    for (int i = 0; i < 8; ++i) {
      int byte = (q * 256 + i * 32 + g * 8) ^ ((q & 7) << 4);
      union { unsigned u[2]; s16x4 v; } w;
      w.u[0] = (unsigned)f2b(s[i][0]) | ((unsigned)f2b(s[i][1]) << 16);
      w.u[1] = (unsigned)f2b(s[i][2]) | ((unsigned)f2b(s[i][3]) << 16);
      *(s16x4*)((char*)Ps[wave] + byte) = w.v;
    }
    __builtin_amdgcn_sched_barrier(0);  // fence: P stores before PV reads

    // O += P @ V over 4 k-slots of 32 keys (A-frag keys kk4*32 + g*8 + e)
#pragma unroll
    for (int kk4 = 0; kk4 < 4; ++kk4) {
      int byteP = (q * 256 + kk4 * 64 + g * 16) ^ ((q & 7) << 4);
      bf16x8 pf = *(const bf16x8*)((char*)Ps[wave] + byteP);
      const u16* Vc = Vs[kk4 >> 1];
#pragma unroll
      for (int nd = 0; nd < 4; ++nd) {
        bf16x8 vf = ldsfrag(Vc, nd * 16 + q, (kk4 & 1) * 4 + g);
        o[nd] = MFMA(pf, vf, o[nd]);
      }
    }
  }

  // epilogue: redistribute 1/l to output rows, O*rcp(l) -> (B, N, nh*hd) bf16
  float lr[4];
#pragma unroll
  for (int r = 0; r < 4; ++r)
    lr[r] = __builtin_amdgcn_rcpf(__shfl(lrun, (lane & 48) | (g * 4 + r)));
#pragma unroll
  for (int nd = 0; nd < 4; ++nd) {
#pragma unroll
    for (int r = 0; r < 4; ++r) {
      int i = qt * 128 + wave * 16 + g * 4 + r;
      int d = nd * 16 + q;
      float val = o[nd][r] * lr[r];
      ao[((size_t)b * 1024 + i) * 768 + h * 64 + d] = f2b(val);
    }
  }
}

// ---------------------------------------------------------------- launcher
extern "C" void kernel_launch(void* const* d_in, const int* in_sizes, int n_in,
                              void* d_out, int out_size, void* d_ws, size_t ws_size,
                              hipStream_t stream) {
  const float* x = (const float*)d_in[0];
  const float* qkvw = (const float*)d_in[1];
  const float* projw = (const float*)d_in[2];
  const float* projb = (const float*)d_in[3];
  const float* btab = (const float*)d_in[4];
  float* out = (float*)d_out;
  char* ws = (char*)d_ws;

  // workspace layout (bytes)
  u16* xb = (u16*)(ws);                    // 8192*768 bf16 = 12,582,912 B
  u16* wqkvT = (u16*)(ws + 12582912);      // 2304*768 bf16 =  3,538,944 B
  u16* wprojT = (u16*)(ws + 16121856);     //  768*768 bf16 =  1,179,648 B
  u16* qbuf = (u16*)(ws + 17301504);       // 12,582,912 B
  u16* kbuf = (u16*)(ws + 29884416);       // 12,582,912 B
  u16* vTbuf = (u16*)(ws + 42467328);      // 12,582,912 B
  u16* biasg = (u16*)(ws + 55050240);      // 12*4096*2 =      98,304 B
  u16* ao = xb;  // reuse: xb dead after QKV GEMM (stream-serialized)

  cast_x_kernel<<<6144, 256, 0, stream>>>(x, xb, 8192 * 768 / 4);
  transpose_cast<<<dim3(72, 24), 256, 0, stream>>>(qkvw, wqkvT, 768, 2304);
  transpose_cast<<<dim3(24, 24), 256, 0, stream>>>(projw, wprojT, 768, 768);
  gather_bias<<<192, 256, 0, stream>>>(btab, biasg);

  gemm128<0><<<dim3(18, 64), 256, 0, stream>>>(xb, wqkvT, 768, qbuf, kbuf,
                                               vTbuf, nullptr, nullptr, 0);

  attn_kernel<<<768, 512, 0, stream>>>(qbuf, kbuf, vTbuf, biasg, ao);

  gemm128<1><<<dim3(6, 64), 256, 0, stream>>>(ao, wprojT, 768, nullptr, nullptr,
                                              nullptr, projb, out, 768);
}

// Round 12
// 172.736 us; speedup vs baseline: 1.5382x; 1.0063x over previous
//
#include <hip/hip_runtime.h>

typedef unsigned short u16;
typedef __attribute__((ext_vector_type(8))) short bf16x8;
typedef __attribute__((ext_vector_type(4))) short s16x4;
typedef __attribute__((ext_vector_type(4))) float f32x4;

#define MFMA(a, b, c) __builtin_amdgcn_mfma_f32_16x16x32_bf16(a, b, c, 0, 0, 0)

// global -> LDS direct copy, 16 B per lane. LDS dest must be wave-uniform base
// (HW adds lane*16). Global source is per-lane.
#define GLDS16(gp, lp)                                                        \
  __builtin_amdgcn_global_load_lds(                                          \
      (__attribute__((address_space(1))) void*)(void*)(gp),                  \
      (__attribute__((address_space(3))) void*)(lp), 16, 0, 0)

__device__ __forceinline__ u16 f2b(float f) {
  union { float f; unsigned u; } x; x.f = f;
  unsigned r = x.u + 0x7fffu + ((x.u >> 16) & 1u);
  return (u16)(r >> 16);
}
__device__ __forceinline__ float b2f(u16 v) {
  union { unsigned u; float f; } x; x.u = ((unsigned)v) << 16;
  return x.f;
}
// pack two f32 -> one u32 of two bf16 (elem0 = a, elem1 = b)
__device__ __forceinline__ unsigned cvtpk(float a, float b) {
  unsigned r;
  asm("v_cvt_pk_bf16_f32 %0, %1, %2" : "=v"(r) : "v"(a), "v"(b));
  return r;
}

// Stage a [32*NPASS rows][64 cols] bf16 tile into LDS with XOR-swizzled SOURCE
// slots so a swizzled ds_read recovers linear data. (256-thread version.)
template <int NPASS>
__device__ __forceinline__ void stage64(const u16* __restrict__ src, int ld,
                                        u16* lds, int t) {
  int wave = t >> 6;
#pragma unroll
  for (int p = 0; p < NPASS; ++p) {
    int row = p * 32 + (t >> 3);
    int ss = (t & 7) ^ (row & 7);
    const u16* g = src + row * ld + ss * 8;
    GLDS16(g, lds + (p * 2048 + wave * 512));
  }
}

// 512-thread version: one pass stages a full 64x64 bf16 tile.
__device__ __forceinline__ void stage512(const u16* __restrict__ src, int ld,
                                         u16* lds, int t) {
  int row = t >> 3;
  int ss = (t & 7) ^ (row & 7);
  GLDS16(src + row * ld + ss * 8, lds + (t >> 6) * 512);
}

// read one MFMA fragment (8 consecutive bf16) at [row][slot*8], swizzle-corrected
__device__ __forceinline__ bf16x8 ldsfrag(const u16* base, int row, int slot) {
  int byte = row * 128 + (((slot) ^ (row & 7)) << 4);
  return *(const bf16x8*)((const char*)base + byte);
}

// ---------------------------------------------------------------- prep kernels
__global__ void cast_x_kernel(const float* __restrict__ in, u16* __restrict__ out,
                              int n4) {
  int i = blockIdx.x * blockDim.x + threadIdx.x;
  if (i < n4) {
    float4 v = ((const float4*)in)[i];
    ushort4 o;
    o.x = f2b(v.x); o.y = f2b(v.y); o.z = f2b(v.z); o.w = f2b(v.w);
    ((ushort4*)out)[i] = o;
  }
}

// out[(c, r)] = bf16(in[(r, c)]); in is (R, Ccols) fp32 row-major.
__global__ void transpose_cast(const float* __restrict__ in, u16* __restrict__ out,
                               int R, int Ccols) {
  __shared__ u16 tile[32][33];
  int c0 = blockIdx.x * 32, r0 = blockIdx.y * 32;
  int tx = threadIdx.x & 31, ty = threadIdx.x >> 5;
#pragma unroll
  for (int rr = ty; rr < 32; rr += 8)
    tile[rr][tx] = f2b(in[(size_t)(r0 + rr) * Ccols + c0 + tx]);
  __syncthreads();
#pragma unroll
  for (int rr = ty; rr < 32; rr += 8)
    out[(size_t)(c0 + rr) * R + r0 + tx] = tile[tx][rr];
}

// bias_table (65025,12) fp32 -> per-head contiguous bf16 [12][4096] (3969 used)
// PRE-SCALED by log2(e): softmax runs in exp2 domain.
__global__ void gather_bias(const float* __restrict__ btab, u16* __restrict__ out) {
  int i = blockIdx.x * 256 + threadIdx.x;  // [0, 12*4096)
  int h = i >> 12, r = i & 4095;
  out[i] = (r < 3969) ? f2b(btab[r * 12 + h] * 1.44269504f) : (u16)0;
}

// ---------------------------------------------------------------- GEMM 128x128
// C = A(M,K) @ BT(N,K)^T, bf16 inputs, fp32 accum.
template <int EPI>
__global__ __launch_bounds__(256, 3) void gemm128(
    const u16* __restrict__ A, const u16* __restrict__ BT, int K,
    u16* __restrict__ qo, u16* __restrict__ ko, u16* __restrict__ vo,
    const float* __restrict__ pb, float* __restrict__ out, int Nld) {
  __shared__ __align__(16) u16 As[128 * 64];
  __shared__ __align__(16) u16 Bs[128 * 64];
  const int t = threadIdx.x;
  const int wave = t >> 6, lane = t & 63;
  const int wr = wave >> 1, wc = wave & 1;
  const int tileRow = blockIdx.y * 128, tileCol = blockIdx.x * 128;
  const u16* Ab = A + (size_t)tileRow * K;
  const u16* Bb = BT + (size_t)tileCol * K;

  f32x4 acc[4][4] = {};
  for (int k0 = 0; k0 < K; k0 += 64) {
    __syncthreads();
    stage64<4>(Ab + k0, K, As, t);
    stage64<4>(Bb + k0, K, Bs, t);
    __syncthreads();
#pragma unroll
    for (int kk = 0; kk < 2; ++kk) {
      bf16x8 af[4], bfr[4];
#pragma unroll
      for (int m = 0; m < 4; ++m)
        af[m] = ldsfrag(As, wr * 64 + m * 16 + (lane & 15), kk * 4 + (lane >> 4));
#pragma unroll
      for (int n = 0; n < 4; ++n)
        bfr[n] = ldsfrag(Bs, wc * 64 + n * 16 + (lane & 15), kk * 4 + (lane >> 4));
#pragma unroll
      for (int m = 0; m < 4; ++m)
#pragma unroll
        for (int n = 0; n < 4; ++n)
          acc[m][n] = MFMA(af[m], bfr[n], acc[m][n]);
    }
  }

#pragma unroll
  for (int m = 0; m < 4; ++m) {
#pragma unroll
    for (int n = 0; n < 4; ++n) {
#pragma unroll
      for (int r = 0; r < 4; ++r) {
        int row = tileRow + wr * 64 + m * 16 + (lane >> 4) * 4 + r;
        int col = tileCol + wc * 64 + n * 16 + (lane & 15);
        float val = acc[m][n][r];
        if (EPI == 0) {
          int which = col / 768;
          int c = col - which * 768;
          int hh = c >> 6, d = c & 63;
          int bb = row >> 10, nn = row & 1023;
          size_t bhnd = ((size_t)(bb * 12 + hh) * 1024 + nn) * 64 + d;
          if (which == 0)
            qo[bhnd] = f2b(val * 0.18033688f);  // 0.125 * log2(e)
          else if (which == 1)
            ko[bhnd] = f2b(val);
          else
            vo[((size_t)(bb * 12 + hh) * 64 + d) * 1024 + nn] = f2b(val);
        } else {
          out[(size_t)row * Nld + col] = val + pb[col];
        }
      }
    }
  }
}

// ---------------------------------------------------------------- attention
// 8-wave blocks, QBLK=128, KVBLK=128, swapped-QK, exp2 domain. Softmax common
// path has ZERO cross-lane ops: rescale trigger uses __any(local_max) (ballot-
// equivalent to row max); lrun is a per-lane partial reduced in the epilogue;
// max/sum shuffles only on the rare rescale path. P tile halved (16x64 reused
// for both 64-key halves) -> LDS 53.6KB -> 3 blocks/CU (grid 768 = 256CUx3).
// grid: 768 flat (XCD-chunked: one batch per XCD); block: 512 (8 waves).
__global__ __launch_bounds__(512, 6) void attn_kernel(
    const u16* __restrict__ qm, const u16* __restrict__ kmat,
    const u16* __restrict__ vT, const u16* __restrict__ bias_g,
    u16* __restrict__ ao) {
  __shared__ __align__(16) u16 bias_s[35 * 64];
  __shared__ __align__(16) u16 Ks[2][64 * 64];
  __shared__ __align__(16) u16 Vs[2][64 * 64];
  __shared__ __align__(16) u16 Ps[8][1024];  // per-wave 16x64 P tile (reused 2x)

  const int t = threadIdx.x;
  const int wave = t >> 6, lane = t & 63;
  const int g = lane >> 4, q = lane & 15;
  // XCD-chunked swizzle: id%8 = XCD, one batch (96 blocks) per XCD.
  const int id = blockIdx.x;
  const int sw = (id & 7) * 96 + (id >> 3);
  const int qt = sw & 7, h = (sw >> 3) % 12, b = sw / 96;
  const int bh = b * 12 + h;

  const u16* kb0 = kmat + (size_t)bh * 1024 * 64;
  const u16* vb0 = vT + (size_t)bh * 64 * 1024;

  // prologue: bias rows dy in [4qt, 4qt+34] (63 cols, stride-64 pad)
  if (t < 280) {
    const u16* bg = bias_g + h * 4096 + qt * 4 * 63;
    GLDS16(bg + (t >> 3) * 63 + (t & 7) * 8, bias_s + (t >> 6) * 512);
  }

  // Q fragments in registers (q pre-scaled by 0.125*log2e); B-operand: col = q
  const u16* qb = qm + ((size_t)bh * 1024 + qt * 128) * 64;
  bf16x8 qf[2];
#pragma unroll
  for (int kk = 0; kk < 2; ++kk)
    qf[kk] = *(const bf16x8*)(qb + (wave * 16 + q) * 64 + kk * 32 + g * 8);

  f32x4 o[4] = {};
  float mrun = -1e30f, lrun = 0.f;  // lrun = PER-LANE partial sum

  // this lane's softmax q-row (for S^T layout)
  const int iq = qt * 128 + wave * 16 + q;
  const int ylq = (wave * 16 + q) >> 5;  // local yi (0..3): yi = 4qt + ylq
  const int xi = iq & 31;

  for (int kt8 = 0; kt8 < 8; ++kt8) {
    __syncthreads();  // all waves done reading K/V (prev round)
    stage512(kb0 + kt8 * 8192, 64, Ks[0], t);
    stage512(kb0 + kt8 * 8192 + 4096, 64, Ks[1], t);
    stage512(vb0 + kt8 * 128, 1024, Vs[0], t);
    stage512(vb0 + kt8 * 128 + 64, 1024, Vs[1], t);
    __syncthreads();  // 128-key tile landed

    // S^T = K @ Q^T over 128 keys: s[half*4+n][r] = S[key][qrow = q],
    // key = half*64 + n*16 + g*4 + r
    f32x4 s[8] = {};
#pragma unroll
    for (int half = 0; half < 2; ++half)
#pragma unroll
      for (int kk = 0; kk < 2; ++kk)
#pragma unroll
        for (int n = 0; n < 4; ++n)
          s[half * 4 + n] =
              MFMA(ldsfrag(Ks[half], n * 16 + q, kk * 4 + g), qf[kk],
                   s[half * 4 + n]);

    // + relative position bias (exp2-domain)
#pragma unroll
    for (int half = 0; half < 2; ++half) {
      const int kt = kt8 * 2 + half;
#pragma unroll
      for (int n = 0; n < 4; ++n) {
        int xj0 = (n & 1) * 16 + g * 4;
        int ldy = ylq - kt * 2 - (n >> 1) + 31;
        int bse = ldy * 64 + (xi - xj0 + 31);
#pragma unroll
        for (int r = 0; r < 4; ++r) s[half * 4 + n][r] += b2f(bias_s[bse - r]);
      }
    }

    // LOCAL max only (31 fmax tree, no shuffles). Wave-wide __any of the
    // local test is ballot-identical to testing each row's full max.
    float mx = -1e30f;
#pragma unroll
    for (int i = 0; i < 8; ++i)
#pragma unroll
      for (int r = 0; r < 4; ++r) mx = fmaxf(mx, s[i][r]);

    if (__any(mx > mrun + 11.5f)) {  // rare path (always on kt8==0)
      float mf = fmaxf(mx, __shfl_xor(mx, 16));
      mf = fmaxf(mf, __shfl_xor(mf, 32));
      float mn = fmaxf(mrun, mf);
      float al = __builtin_amdgcn_exp2f(mrun - mn);
      mrun = mn;
      lrun *= al;
#pragma unroll
      for (int r = 0; r < 4; ++r) {
        float ar = __shfl(al, (lane & 48) | (g * 4 + r));
#pragma unroll
        for (int nd = 0; nd < 4; ++nd) o[nd][r] *= ar;
      }
    }

    // exp2 + per-lane partial sum (no cross-lane)
#pragma unroll
    for (int i = 0; i < 8; ++i)
#pragma unroll
      for (int r = 0; r < 4; ++r) {
        float p = __builtin_amdgcn_exp2f(s[i][r] - mrun);
        s[i][r] = p;
        lrun += p;
      }

    // two 64-key halves share one 16x64 P tile: pack -> write -> PV, twice
#pragma unroll
    for (int hp = 0; hp < 2; ++hp) {
#pragma unroll
      for (int i = 0; i < 4; ++i) {
        int byte = (q * 128 + i * 32 + g * 8) ^ ((q & 7) << 4);
        union { unsigned u[2]; s16x4 v; } w;
        w.u[0] = cvtpk(s[hp * 4 + i][0], s[hp * 4 + i][1]);
        w.u[1] = cvtpk(s[hp * 4 + i][2], s[hp * 4 + i][3]);
        *(s16x4*)((char*)Ps[wave] + byte) = w.v;
      }
      __builtin_amdgcn_sched_barrier(0);  // P writes before PV reads
#pragma unroll
      for (int kk = 0; kk < 2; ++kk) {
        int byteP = (q * 128 + kk * 64 + g * 16) ^ ((q & 7) << 4);
        bf16x8 pf = *(const bf16x8*)((char*)Ps[wave] + byteP);
#pragma unroll
        for (int nd = 0; nd < 4; ++nd) {
          bf16x8 vf = ldsfrag(Vs[hp], nd * 16 + q, kk * 4 + g);
          o[nd] = MFMA(pf, vf, o[nd]);
        }
      }
      __builtin_amdgcn_sched_barrier(0);  // PV reads before next half's writes
    }
  }

  // epilogue: reduce lrun partials across the row, redistribute rcp(l) to
  // output rows, O*rcp(l) -> (B, N, nh*hd) bf16
  lrun += __shfl_xor(lrun, 16);
  lrun += __shfl_xor(lrun, 32);
  float lr[4];
#pragma unroll
  for (int r = 0; r < 4; ++r)
    lr[r] = __builtin_amdgcn_rcpf(__shfl(lrun, (lane & 48) | (g * 4 + r)));
#pragma unroll
  for (int nd = 0; nd < 4; ++nd) {
#pragma unroll
    for (int r = 0; r < 4; ++r) {
      int i = qt * 128 + wave * 16 + g * 4 + r;
      int d = nd * 16 + q;
      float val = o[nd][r] * lr[r];
      ao[((size_t)b * 1024 + i) * 768 + h * 64 + d] = f2b(val);
    }
  }
}

// ---------------------------------------------------------------- launcher
extern "C" void kernel_launch(void* const* d_in, const int* in_sizes, int n_in,
                              void* d_out, int out_size, void* d_ws, size_t ws_size,
                              hipStream_t stream) {
  const float* x = (const float*)d_in[0];
  const float* qkvw = (const float*)d_in[1];
  const float* projw = (const float*)d_in[2];
  const float* projb = (const float*)d_in[3];
  const float* btab = (const float*)d_in[4];
  float* out = (float*)d_out;
  char* ws = (char*)d_ws;

  // workspace layout (bytes)
  u16* xb = (u16*)(ws);                    // 8192*768 bf16 = 12,582,912 B
  u16* wqkvT = (u16*)(ws + 12582912);      // 2304*768 bf16 =  3,538,944 B
  u16* wprojT = (u16*)(ws + 16121856);     //  768*768 bf16 =  1,179,648 B
  u16* qbuf = (u16*)(ws + 17301504);       // 12,582,912 B
  u16* kbuf = (u16*)(ws + 29884416);       // 12,582,912 B
  u16* vTbuf = (u16*)(ws + 42467328);      // 12,582,912 B
  u16* biasg = (u16*)(ws + 55050240);      // 12*4096*2 =      98,304 B
  u16* ao = xb;  // reuse: xb dead after QKV GEMM (stream-serialized)

  cast_x_kernel<<<6144, 256, 0, stream>>>(x, xb, 8192 * 768 / 4);
  transpose_cast<<<dim3(72, 24), 256, 0, stream>>>(qkvw, wqkvT, 768, 2304);
  transpose_cast<<<dim3(24, 24), 256, 0, stream>>>(projw, wprojT, 768, 768);
  gather_bias<<<192, 256, 0, stream>>>(btab, biasg);

  gemm128<0><<<dim3(18, 64), 256, 0, stream>>>(xb, wqkvT, 768, qbuf, kbuf,
                                               vTbuf, nullptr, nullptr, 0);

  attn_kernel<<<768, 512, 0, stream>>>(qbuf, kbuf, vTbuf, biasg, ao);

  gemm128<1><<<dim3(6, 64), 256, 0, stream>>>(ao, wprojT, 768, nullptr, nullptr,
                                              nullptr, projb, out, 768);
}

// Round 13
// 168.477 us; speedup vs baseline: 1.5771x; 1.0253x over previous
//
#include <hip/hip_runtime.h>

typedef unsigned short u16;
typedef __attribute__((ext_vector_type(8))) short bf16x8;
typedef __attribute__((ext_vector_type(4))) short s16x4;
typedef __attribute__((ext_vector_type(4))) float f32x4;
typedef __attribute__((ext_vector_type(16))) float f32x16;

#define MFMA(a, b, c) __builtin_amdgcn_mfma_f32_16x16x32_bf16(a, b, c, 0, 0, 0)
#define MFMA32(a, b, c) __builtin_amdgcn_mfma_f32_32x32x16_bf16(a, b, c, 0, 0, 0)

// global -> LDS direct copy, 16 B per lane. LDS dest must be wave-uniform base
// (HW adds lane*16). Global source is per-lane.
#define GLDS16(gp, lp)                                                        \
  __builtin_amdgcn_global_load_lds(                                          \
      (__attribute__((address_space(1))) void*)(void*)(gp),                  \
      (__attribute__((address_space(3))) void*)(lp), 16, 0, 0)

__device__ __forceinline__ u16 f2b(float f) {
  union { float f; unsigned u; } x; x.f = f;
  unsigned r = x.u + 0x7fffu + ((x.u >> 16) & 1u);
  return (u16)(r >> 16);
}
__device__ __forceinline__ float b2f(u16 v) {
  union { unsigned u; float f; } x; x.u = ((unsigned)v) << 16;
  return x.f;
}
// pack two f32 -> one u32 of two bf16 (elem0 = a, elem1 = b)
__device__ __forceinline__ unsigned cvtpk(float a, float b) {
  unsigned r;
  asm("v_cvt_pk_bf16_f32 %0, %1, %2" : "=v"(r) : "v"(a), "v"(b));
  return r;
}

// Stage a [32*NPASS rows][64 cols] bf16 tile into LDS with XOR-swizzled SOURCE
// slots so a swizzled ds_read recovers linear data. (256-thread version.)
template <int NPASS>
__device__ __forceinline__ void stage64(const u16* __restrict__ src, int ld,
                                        u16* lds, int t) {
  int wave = t >> 6;
#pragma unroll
  for (int p = 0; p < NPASS; ++p) {
    int row = p * 32 + (t >> 3);
    int ss = (t & 7) ^ (row & 7);
    const u16* g = src + row * ld + ss * 8;
    GLDS16(g, lds + (p * 2048 + wave * 512));
  }
}

// read one MFMA fragment (8 consecutive bf16) at [row][slot*8], swizzle-corrected
__device__ __forceinline__ bf16x8 ldsfrag(const u16* base, int row, int slot) {
  int byte = row * 128 + (((slot) ^ (row & 7)) << 4);
  return *(const bf16x8*)((const char*)base + byte);
}

// ---------------------------------------------------------------- prep kernels
__global__ void cast_x_kernel(const float* __restrict__ in, u16* __restrict__ out,
                              int n4) {
  int i = blockIdx.x * blockDim.x + threadIdx.x;
  if (i < n4) {
    float4 v = ((const float4*)in)[i];
    ushort4 o;
    o.x = f2b(v.x); o.y = f2b(v.y); o.z = f2b(v.z); o.w = f2b(v.w);
    ((ushort4*)out)[i] = o;
  }
}

// out[(c, r)] = bf16(in[(r, c)]); in is (R, Ccols) fp32 row-major.
__global__ void transpose_cast(const float* __restrict__ in, u16* __restrict__ out,
                               int R, int Ccols) {
  __shared__ u16 tile[32][33];
  int c0 = blockIdx.x * 32, r0 = blockIdx.y * 32;
  int tx = threadIdx.x & 31, ty = threadIdx.x >> 5;
#pragma unroll
  for (int rr = ty; rr < 32; rr += 8)
    tile[rr][tx] = f2b(in[(size_t)(r0 + rr) * Ccols + c0 + tx]);
  __syncthreads();
#pragma unroll
  for (int rr = ty; rr < 32; rr += 8)
    out[(size_t)(c0 + rr) * R + r0 + tx] = tile[tx][rr];
}

// bias_table (65025,12) fp32 -> per-head contiguous bf16 [12][4096] (3969 used)
// PRE-SCALED by log2(e): softmax runs in exp2 domain.
__global__ void gather_bias(const float* __restrict__ btab, u16* __restrict__ out) {
  int i = blockIdx.x * 256 + threadIdx.x;  // [0, 12*4096)
  int h = i >> 12, r = i & 4095;
  out[i] = (r < 3969) ? f2b(btab[r * 12 + h] * 1.44269504f) : (u16)0;
}

// ---------------------------------------------------------------- GEMM 128x128
// C = A(M,K) @ BT(N,K)^T, bf16 inputs, fp32 accum.
template <int EPI>
__global__ __launch_bounds__(256, 3) void gemm128(
    const u16* __restrict__ A, const u16* __restrict__ BT, int K,
    u16* __restrict__ qo, u16* __restrict__ ko, u16* __restrict__ vo,
    const float* __restrict__ pb, float* __restrict__ out, int Nld) {
  __shared__ __align__(16) u16 As[128 * 64];
  __shared__ __align__(16) u16 Bs[128 * 64];
  const int t = threadIdx.x;
  const int wave = t >> 6, lane = t & 63;
  const int wr = wave >> 1, wc = wave & 1;
  const int tileRow = blockIdx.y * 128, tileCol = blockIdx.x * 128;
  const u16* Ab = A + (size_t)tileRow * K;
  const u16* Bb = BT + (size_t)tileCol * K;

  f32x4 acc[4][4] = {};
  for (int k0 = 0; k0 < K; k0 += 64) {
    __syncthreads();
    stage64<4>(Ab + k0, K, As, t);
    stage64<4>(Bb + k0, K, Bs, t);
    __syncthreads();
#pragma unroll
    for (int kk = 0; kk < 2; ++kk) {
      bf16x8 af[4], bfr[4];
#pragma unroll
      for (int m = 0; m < 4; ++m)
        af[m] = ldsfrag(As, wr * 64 + m * 16 + (lane & 15), kk * 4 + (lane >> 4));
#pragma unroll
      for (int n = 0; n < 4; ++n)
        bfr[n] = ldsfrag(Bs, wc * 64 + n * 16 + (lane & 15), kk * 4 + (lane >> 4));
#pragma unroll
      for (int m = 0; m < 4; ++m)
#pragma unroll
        for (int n = 0; n < 4; ++n)
          acc[m][n] = MFMA(af[m], bfr[n], acc[m][n]);
    }
  }

#pragma unroll
  for (int m = 0; m < 4; ++m) {
#pragma unroll
    for (int n = 0; n < 4; ++n) {
#pragma unroll
      for (int r = 0; r < 4; ++r) {
        int row = tileRow + wr * 64 + m * 16 + (lane >> 4) * 4 + r;
        int col = tileCol + wc * 64 + n * 16 + (lane & 15);
        float val = acc[m][n][r];
        if (EPI == 0) {
          int which = col / 768;
          int c = col - which * 768;
          int hh = c >> 6, d = c & 63;
          int bb = row >> 10, nn = row & 1023;
          size_t bhnd = ((size_t)(bb * 12 + hh) * 1024 + nn) * 64 + d;
          if (which == 0)
            qo[bhnd] = f2b(val * 0.18033688f);  // 0.125 * log2(e)
          else if (which == 1)
            ko[bhnd] = f2b(val);
          else
            vo[((size_t)(bb * 12 + hh) * 64 + d) * 1024 + nn] = f2b(val);
        } else {
          out[(size_t)row * Nld + col] = val + pb[col];
        }
      }
    }
  }
}

// ---------------------------------------------------------------- attention
// 32x32x16 MFMA version: 4 waves x 32 q-rows (QBLK=128), KVBLK=128. Halves
// the dominant ds_read_b128 count per block-iter (DS pipe was ~60% busy).
// Swapped-QK: S^T = K @ Q^T -> lane owns q-row (lane&31) for BOTH softmax
// and the PV A-operand. C/D: col=lane&31, row=(e&3)+8*(e>>2)+4*(lane>>5).
// grid: 768 flat (XCD-chunked: one batch per XCD); block: 256 (4 waves).
__global__ __launch_bounds__(256, 3) void attn_kernel(
    const u16* __restrict__ qm, const u16* __restrict__ kmat,
    const u16* __restrict__ vT, const u16* __restrict__ bias_g,
    u16* __restrict__ ao) {
  __shared__ __align__(16) u16 bias_s[35 * 64];
  __shared__ __align__(16) u16 Ks[2][64 * 64];
  __shared__ __align__(16) u16 Vs[2][64 * 64];
  __shared__ __align__(16) u16 Ps[4][32 * 64];  // per-wave 32x64 P tile

  const int t = threadIdx.x;
  const int wv = t >> 6, lane = t & 63;
  const int hi = lane >> 5, q = lane & 31;
  // XCD-chunked swizzle: id%8 = XCD, one batch (96 blocks) per XCD.
  const int id = blockIdx.x;
  const int sw = (id & 7) * 96 + (id >> 3);
  const int qt = sw & 7, h = (sw >> 3) % 12, b = sw / 96;
  const int bh = b * 12 + h;

  const u16* kb0 = kmat + (size_t)bh * 1024 * 64;
  const u16* vb0 = vT + (size_t)bh * 64 * 1024;

  // prologue: bias rows dy in [4qt, 4qt+34] (63 cols, stride-64 pad).
  // 280 16B-slots: 256 threads cover slots 0-255, wave0 lanes 0-23 the rest.
  {
    const u16* bg = bias_g + h * 4096 + qt * 4 * 63;
    GLDS16(bg + (t >> 3) * 63 + (t & 7) * 8, bias_s + wv * 512);
    if (t < 24)
      GLDS16(bg + (32 + (t >> 3)) * 63 + (t & 7) * 8, bias_s + 2048);
  }

  // Q fragments (q pre-scaled by 0.125*log2e). B-operand: col = q-row = lane&31,
  // k = (lane>>5)*8 + i within d-block of 16.
  const u16* qb = qm + ((size_t)bh * 1024 + qt * 128 + wv * 32) * 64;
  bf16x8 qf[4];
#pragma unroll
  for (int dblk = 0; dblk < 4; ++dblk)
    qf[dblk] = *(const bf16x8*)(qb + q * 64 + dblk * 16 + hi * 8);

  f32x16 o32[2] = {};                 // O[32q x 64d]: 2 d-blocks of 32
  float mrun = -1e30f, lrun = 0.f;    // per-lane partial sum (64 of 128 keys)

  const int yi_loc = wv;  // yi = 4qt + wv; xi = q

  for (int kt8 = 0; kt8 < 8; ++kt8) {
    __syncthreads();  // all waves done reading K/V (prev round)
    stage64<2>(kb0 + kt8 * 8192, 64, Ks[0], t);
    stage64<2>(kb0 + kt8 * 8192 + 4096, 64, Ks[1], t);
    stage64<2>(vb0 + kt8 * 128, 1024, Vs[0], t);
    stage64<2>(vb0 + kt8 * 128 + 64, 1024, Vs[1], t);
    __syncthreads();  // 128-key tile landed

    // S^T = K @ Q^T: s4[kb] covers keys kb*32 + (e&3)+8*(e>>2)+4*hi, q-col = q
    f32x16 s4[4] = {};
#pragma unroll
    for (int kb = 0; kb < 4; ++kb) {
      const u16* Kc = Ks[kb >> 1];
      int krow = (kb & 1) * 32 + q;
#pragma unroll
      for (int dblk = 0; dblk < 4; ++dblk) {
        bf16x8 kf = ldsfrag(Kc, krow, dblk * 2 + hi);
        s4[kb] = MFMA32(kf, qf[dblk], s4[kb]);
      }
    }

    // + relative position bias (exp2-domain); dy const per kb, dx descending
#pragma unroll
    for (int kb = 0; kb < 4; ++kb) {
      int ldy = yi_loc - kt8 * 4 - kb + 31;
      int base = ldy * 64 + q + 31 - 4 * hi;
#pragma unroll
      for (int e2 = 0; e2 < 4; ++e2) {
        int bse = base - 8 * e2;
#pragma unroll
        for (int e3 = 0; e3 < 4; ++e3)
          s4[kb][e2 * 4 + e3] += b2f(bias_s[bse - e3]);
      }
    }

    // LOCAL max (63 fmax, no shuffles); __any is ballot-equivalent to row test
    float mx = -1e30f;
#pragma unroll
    for (int kb = 0; kb < 4; ++kb)
#pragma unroll
      for (int e = 0; e < 16; ++e) mx = fmaxf(mx, s4[kb][e]);

    if (__any(mx > mrun + 11.5f)) {  // rare path
      float mf = fmaxf(mx, __shfl_xor(mx, 32));
      float mn = fmaxf(mrun, mf);
      float al = __builtin_amdgcn_exp2f(mrun - mn);
      mrun = mn;
      lrun *= al;
#pragma unroll
      for (int e = 0; e < 16; ++e) {
        int qr = (e & 3) + 8 * (e >> 2) + 4 * hi;
        float ar = __shfl(al, qr);
        o32[0][e] *= ar;
        o32[1][e] *= ar;
      }
    }

    // exp2 + per-lane partial sum
#pragma unroll
    for (int kb = 0; kb < 4; ++kb)
#pragma unroll
      for (int e = 0; e < 16; ++e) {
        float p = __builtin_amdgcn_exp2f(s4[kb][e] - mrun);
        s4[kb][e] = p;
        lrun += p;
      }

    // two 64-key halves share one 32x64 P tile: pack -> write -> PV, twice
#pragma unroll
    for (int hp = 0; hp < 2; ++hp) {
#pragma unroll
      for (int kbl = 0; kbl < 2; ++kbl) {
        const f32x16& sv = s4[hp * 2 + kbl];
#pragma unroll
        for (int e2 = 0; e2 < 4; ++e2) {
          int jb = kbl * 32 + 8 * e2 + 4 * hi;
          int byte = (q * 128 + jb * 2) ^ ((q & 7) << 4);
          union { unsigned u[2]; s16x4 v; } w;
          w.u[0] = cvtpk(sv[e2 * 4 + 0], sv[e2 * 4 + 1]);
          w.u[1] = cvtpk(sv[e2 * 4 + 2], sv[e2 * 4 + 3]);
          *(s16x4*)((char*)Ps[wv] + byte) = w.v;
        }
      }
      __builtin_amdgcn_sched_barrier(0);  // P writes before PV reads
#pragma unroll
      for (int kblk = 0; kblk < 4; ++kblk) {
        bf16x8 pf = ldsfrag(Ps[wv], q, kblk * 2 + hi);
#pragma unroll
        for (int dblk = 0; dblk < 2; ++dblk) {
          bf16x8 vf = ldsfrag(Vs[hp], dblk * 32 + q, kblk * 2 + hi);
          o32[dblk] = MFMA32(pf, vf, o32[dblk]);
        }
      }
      __builtin_amdgcn_sched_barrier(0);  // PV reads before next half's writes
    }
  }

  // epilogue: complete row sums, O*rcp(l) -> (B, N, nh*hd) bf16
  lrun += __shfl_xor(lrun, 32);
#pragma unroll
  for (int e = 0; e < 16; ++e) {
    int qr = (e & 3) + 8 * (e >> 2) + 4 * hi;
    float lv = __builtin_amdgcn_rcpf(__shfl(lrun, qr));
    int i = qt * 128 + wv * 32 + qr;
#pragma unroll
    for (int dblk = 0; dblk < 2; ++dblk) {
      int d = dblk * 32 + q;
      float val = o32[dblk][e] * lv;
      ao[((size_t)b * 1024 + i) * 768 + h * 64 + d] = f2b(val);
    }
  }
}

// ---------------------------------------------------------------- launcher
extern "C" void kernel_launch(void* const* d_in, const int* in_sizes, int n_in,
                              void* d_out, int out_size, void* d_ws, size_t ws_size,
                              hipStream_t stream) {
  const float* x = (const float*)d_in[0];
  const float* qkvw = (const float*)d_in[1];
  const float* projw = (const float*)d_in[2];
  const float* projb = (const float*)d_in[3];
  const float* btab = (const float*)d_in[4];
  float* out = (float*)d_out;
  char* ws = (char*)d_ws;

  // workspace layout (bytes)
  u16* xb = (u16*)(ws);                    // 8192*768 bf16 = 12,582,912 B
  u16* wqkvT = (u16*)(ws + 12582912);      // 2304*768 bf16 =  3,538,944 B
  u16* wprojT = (u16*)(ws + 16121856);     //  768*768 bf16 =  1,179,648 B
  u16* qbuf = (u16*)(ws + 17301504);       // 12,582,912 B
  u16* kbuf = (u16*)(ws + 29884416);       // 12,582,912 B
  u16* vTbuf = (u16*)(ws + 42467328);      // 12,582,912 B
  u16* biasg = (u16*)(ws + 55050240);      // 12*4096*2 =      98,304 B
  u16* ao = xb;  // reuse: xb dead after QKV GEMM (stream-serialized)

  cast_x_kernel<<<6144, 256, 0, stream>>>(x, xb, 8192 * 768 / 4);
  transpose_cast<<<dim3(72, 24), 256, 0, stream>>>(qkvw, wqkvT, 768, 2304);
  transpose_cast<<<dim3(24, 24), 256, 0, stream>>>(projw, wprojT, 768, 768);
  gather_bias<<<192, 256, 0, stream>>>(btab, biasg);

  gemm128<0><<<dim3(18, 64), 256, 0, stream>>>(xb, wqkvT, 768, qbuf, kbuf,
                                               vTbuf, nullptr, nullptr, 0);

  attn_kernel<<<768, 256, 0, stream>>>(qbuf, kbuf, vTbuf, biasg, ao);

  gemm128<1><<<dim3(6, 64), 256, 0, stream>>>(ao, wprojT, 768, nullptr, nullptr,
                                              nullptr, projb, out, 768);
}

// Round 14
// 152.856 us; speedup vs baseline: 1.7383x; 1.1022x over previous
//
#include <hip/hip_runtime.h>

typedef unsigned short u16;
typedef __attribute__((ext_vector_type(8))) short bf16x8;
typedef __attribute__((ext_vector_type(4))) short s16x4;
typedef __attribute__((ext_vector_type(4))) float f32x4;
typedef __attribute__((ext_vector_type(16))) float f32x16;

#define MFMA(a, b, c) __builtin_amdgcn_mfma_f32_16x16x32_bf16(a, b, c, 0, 0, 0)
#define MFMA32(a, b, c) __builtin_amdgcn_mfma_f32_32x32x16_bf16(a, b, c, 0, 0, 0)

// global -> LDS direct copy, 16 B per lane. LDS dest must be wave-uniform base
// (HW adds lane*16). Global source is per-lane.
#define GLDS16(gp, lp)                                                        \
  __builtin_amdgcn_global_load_lds(                                          \
      (__attribute__((address_space(1))) void*)(void*)(gp),                  \
      (__attribute__((address_space(3))) void*)(lp), 16, 0, 0)

__device__ __forceinline__ u16 f2b(float f) {
  union { float f; unsigned u; } x; x.f = f;
  unsigned r = x.u + 0x7fffu + ((x.u >> 16) & 1u);
  return (u16)(r >> 16);
}
__device__ __forceinline__ float b2f(u16 v) {
  union { unsigned u; float f; } x; x.u = ((unsigned)v) << 16;
  return x.f;
}
// pack two f32 -> one u32 of two bf16 (elem0 = a, elem1 = b)
__device__ __forceinline__ unsigned cvtpk(float a, float b) {
  unsigned r;
  asm("v_cvt_pk_bf16_f32 %0, %1, %2" : "=v"(r) : "v"(a), "v"(b));
  return r;
}

// Stage a [32*NPASS rows][64 cols] bf16 tile into LDS with XOR-swizzled SOURCE
// slots so a swizzled ds_read recovers linear data. (256-thread version.)
template <int NPASS>
__device__ __forceinline__ void stage64(const u16* __restrict__ src, int ld,
                                        u16* lds, int t) {
  int wave = t >> 6;
#pragma unroll
  for (int p = 0; p < NPASS; ++p) {
    int row = p * 32 + (t >> 3);
    int ss = (t & 7) ^ (row & 7);
    const u16* g = src + row * ld + ss * 8;
    GLDS16(g, lds + (p * 2048 + wave * 512));
  }
}

// read one MFMA fragment (8 consecutive bf16) at [row][slot*8], swizzle-corrected
__device__ __forceinline__ bf16x8 ldsfrag(const u16* base, int row, int slot) {
  int byte = row * 128 + (((slot) ^ (row & 7)) << 4);
  return *(const bf16x8*)((const char*)base + byte);
}

// ---------------------------------------------------------------- prep kernels
__global__ void cast_x_kernel(const float* __restrict__ in, u16* __restrict__ out,
                              int n4) {
  int i = blockIdx.x * blockDim.x + threadIdx.x;
  if (i < n4) {
    float4 v = ((const float4*)in)[i];
    ushort4 o;
    o.x = f2b(v.x); o.y = f2b(v.y); o.z = f2b(v.z); o.w = f2b(v.w);
    ((ushort4*)out)[i] = o;
  }
}

// out[(c, r)] = bf16(in[(r, c)]); in is (R, Ccols) fp32 row-major.
__global__ void transpose_cast(const float* __restrict__ in, u16* __restrict__ out,
                               int R, int Ccols) {
  __shared__ u16 tile[32][33];
  int c0 = blockIdx.x * 32, r0 = blockIdx.y * 32;
  int tx = threadIdx.x & 31, ty = threadIdx.x >> 5;
#pragma unroll
  for (int rr = ty; rr < 32; rr += 8)
    tile[rr][tx] = f2b(in[(size_t)(r0 + rr) * Ccols + c0 + tx]);
  __syncthreads();
#pragma unroll
  for (int rr = ty; rr < 32; rr += 8)
    out[(size_t)(c0 + rr) * R + r0 + tx] = tile[tx][rr];
}

// bias_table (65025,12) fp32 -> lane-order-expanded bf16 biasx[h][dy][q][p]:
// p = e + 16*hi encodes the 32x32 MFMA C/D row j31 = (e&3)+8*(e>>2)+4*hi;
// value = bias[dy][q + 31 - j31] * log2(e). 12*63*32*32 u16 = 1.5 MB.
__global__ void gather_bias(const float* __restrict__ btab, u16* __restrict__ out) {
  int i = blockIdx.x * 256 + threadIdx.x;  // [0, 12*63*32*32)
  int p = i & 31, q = (i >> 5) & 31, dy = (i >> 10) % 63, h = i / (63 * 1024);
  int hi = p >> 4, e = p & 15;
  int j31 = (e & 3) + 8 * (e >> 2) + 4 * hi;
  int dx = q + 31 - j31;  // always in [0, 62]
  out[i] = f2b(btab[(dy * 63 + dx) * 12 + h] * 1.44269504f);
}

// ---------------------------------------------------------------- GEMM 128x128
// C = A(M,K) @ BT(N,K)^T, bf16 inputs, fp32 accum.
template <int EPI>
__global__ __launch_bounds__(256, 3) void gemm128(
    const u16* __restrict__ A, const u16* __restrict__ BT, int K,
    u16* __restrict__ qo, u16* __restrict__ ko, u16* __restrict__ vo,
    const float* __restrict__ pb, float* __restrict__ out, int Nld) {
  __shared__ __align__(16) u16 As[128 * 64];
  __shared__ __align__(16) u16 Bs[128 * 64];
  const int t = threadIdx.x;
  const int wave = t >> 6, lane = t & 63;
  const int wr = wave >> 1, wc = wave & 1;
  const int tileRow = blockIdx.y * 128, tileCol = blockIdx.x * 128;
  const u16* Ab = A + (size_t)tileRow * K;
  const u16* Bb = BT + (size_t)tileCol * K;

  f32x4 acc[4][4] = {};
  for (int k0 = 0; k0 < K; k0 += 64) {
    __syncthreads();
    stage64<4>(Ab + k0, K, As, t);
    stage64<4>(Bb + k0, K, Bs, t);
    __syncthreads();
#pragma unroll
    for (int kk = 0; kk < 2; ++kk) {
      bf16x8 af[4], bfr[4];
#pragma unroll
      for (int m = 0; m < 4; ++m)
        af[m] = ldsfrag(As, wr * 64 + m * 16 + (lane & 15), kk * 4 + (lane >> 4));
#pragma unroll
      for (int n = 0; n < 4; ++n)
        bfr[n] = ldsfrag(Bs, wc * 64 + n * 16 + (lane & 15), kk * 4 + (lane >> 4));
#pragma unroll
      for (int m = 0; m < 4; ++m)
#pragma unroll
        for (int n = 0; n < 4; ++n)
          acc[m][n] = MFMA(af[m], bfr[n], acc[m][n]);
    }
  }

#pragma unroll
  for (int m = 0; m < 4; ++m) {
#pragma unroll
    for (int n = 0; n < 4; ++n) {
#pragma unroll
      for (int r = 0; r < 4; ++r) {
        int row = tileRow + wr * 64 + m * 16 + (lane >> 4) * 4 + r;
        int col = tileCol + wc * 64 + n * 16 + (lane & 15);
        float val = acc[m][n][r];
        if (EPI == 0) {
          int which = col / 768;
          int c = col - which * 768;
          int hh = c >> 6, d = c & 63;
          int bb = row >> 10, nn = row & 1023;
          size_t bhnd = ((size_t)(bb * 12 + hh) * 1024 + nn) * 64 + d;
          if (which == 0)
            qo[bhnd] = f2b(val * 0.18033688f);  // 0.125 * log2(e)
          else if (which == 1)
            ko[bhnd] = f2b(val);
          else
            vo[((size_t)(bb * 12 + hh) * 64 + d) * 1024 + nn] = f2b(val);
        } else {
          out[(size_t)row * Nld + col] = val + pb[col];
        }
      }
    }
  }
}

// ---------------------------------------------------------------- attention
// 32x32x16 MFMA, 4 waves x 32 q-rows (QBLK=128), KVBLK=128. Bias comes from
// the lane-order-expanded GLOBAL table biasx (L2-resident, two aligned 16B
// coalesced loads per kb) -- removes the 64 ds_read_u16/wave-iter that
// saturated the DS pipe. LDS holds only K/V tiles + wave-local P (48 KB).
// grid: 768 flat (XCD-chunked: one batch per XCD); block: 256 (4 waves).
__global__ __launch_bounds__(256, 3) void attn_kernel(
    const u16* __restrict__ qm, const u16* __restrict__ kmat,
    const u16* __restrict__ vT, const u16* __restrict__ biasx,
    u16* __restrict__ ao) {
  __shared__ __align__(16) u16 Ks[2][64 * 64];
  __shared__ __align__(16) u16 Vs[2][64 * 64];
  __shared__ __align__(16) u16 Ps[4][32 * 64];  // per-wave 32x64 P tile

  const int t = threadIdx.x;
  const int wv = t >> 6, lane = t & 63;
  const int hi = lane >> 5, q = lane & 31;
  // XCD-chunked swizzle: id%8 = XCD, one batch (96 blocks) per XCD.
  const int id = blockIdx.x;
  const int sw = (id & 7) * 96 + (id >> 3);
  const int qt = sw & 7, h = (sw >> 3) % 12, b = sw / 96;
  const int bh = b * 12 + h;

  const u16* kb0 = kmat + (size_t)bh * 1024 * 64;
  const u16* vb0 = vT + (size_t)bh * 64 * 1024;
  // per-lane bias base: biasx[h][*][q][hi*16]
  const u16* bx0 = biasx + (((size_t)h * 63) * 32 + q) * 32 + hi * 16;

  // Q fragments (q pre-scaled by 0.125*log2e). B-operand: col = q-row = lane&31,
  // k = (lane>>5)*8 + i within d-block of 16.
  const u16* qb = qm + ((size_t)bh * 1024 + qt * 128 + wv * 32) * 64;
  bf16x8 qf[4];
#pragma unroll
  for (int dblk = 0; dblk < 4; ++dblk)
    qf[dblk] = *(const bf16x8*)(qb + q * 64 + dblk * 16 + hi * 8);

  f32x16 o32[2] = {};                 // O[32q x 64d]: 2 d-blocks of 32
  float mrun = -1e30f, lrun = 0.f;    // per-lane partial sum (64 of 128 keys)

  const int ldy0 = wv + qt * 4 + 31;  // ldy = ldy0 - kt8*4 - kb, in [0,62]

  for (int kt8 = 0; kt8 < 8; ++kt8) {
    __syncthreads();  // all waves done reading K/V (prev round)
    stage64<2>(kb0 + kt8 * 8192, 64, Ks[0], t);
    stage64<2>(kb0 + kt8 * 8192 + 4096, 64, Ks[1], t);
    stage64<2>(vb0 + kt8 * 128, 1024, Vs[0], t);
    stage64<2>(vb0 + kt8 * 128 + 64, 1024, Vs[1], t);

    // bias fragments from global (L2-hit, coalesced); overlap with DMA
    bf16x8 bb[4][2];
#pragma unroll
    for (int kb = 0; kb < 4; ++kb) {
      const u16* bp = bx0 + (size_t)(ldy0 - kt8 * 4 - kb) * 1024;
      bb[kb][0] = *(const bf16x8*)(bp);
      bb[kb][1] = *(const bf16x8*)(bp + 8);
    }
    __syncthreads();  // 128-key tile landed

    // S^T = K @ Q^T: s4[kb] covers keys kb*32 + (e&3)+8*(e>>2)+4*hi, q-col = q
    f32x16 s4[4] = {};
#pragma unroll
    for (int kb = 0; kb < 4; ++kb) {
      const u16* Kc = Ks[kb >> 1];
      int krow = (kb & 1) * 32 + q;
#pragma unroll
      for (int dblk = 0; dblk < 4; ++dblk) {
        bf16x8 kf = ldsfrag(Kc, krow, dblk * 2 + hi);
        s4[kb] = MFMA32(kf, qf[dblk], s4[kb]);
      }
    }

    // + relative position bias (exp2-domain), from registers
#pragma unroll
    for (int kb = 0; kb < 4; ++kb)
#pragma unroll
      for (int e = 0; e < 16; ++e)
        s4[kb][e] += b2f((u16)(e < 8 ? bb[kb][0][e] : bb[kb][1][e - 8]));

    // LOCAL max (63 fmax, no shuffles); __any is ballot-equivalent to row test
    float mx = -1e30f;
#pragma unroll
    for (int kb = 0; kb < 4; ++kb)
#pragma unroll
      for (int e = 0; e < 16; ++e) mx = fmaxf(mx, s4[kb][e]);

    if (__any(mx > mrun + 11.5f)) {  // rare path
      float mf = fmaxf(mx, __shfl_xor(mx, 32));
      float mn = fmaxf(mrun, mf);
      float al = __builtin_amdgcn_exp2f(mrun - mn);
      mrun = mn;
      lrun *= al;
#pragma unroll
      for (int e = 0; e < 16; ++e) {
        int qr = (e & 3) + 8 * (e >> 2) + 4 * hi;
        float ar = __shfl(al, qr);
        o32[0][e] *= ar;
        o32[1][e] *= ar;
      }
    }

    // exp2 + per-lane partial sum
#pragma unroll
    for (int kb = 0; kb < 4; ++kb)
#pragma unroll
      for (int e = 0; e < 16; ++e) {
        float p = __builtin_amdgcn_exp2f(s4[kb][e] - mrun);
        s4[kb][e] = p;
        lrun += p;
      }

    // two 64-key halves share one 32x64 P tile: pack -> write -> PV, twice
#pragma unroll
    for (int hp = 0; hp < 2; ++hp) {
#pragma unroll
      for (int kbl = 0; kbl < 2; ++kbl) {
        const f32x16& sv = s4[hp * 2 + kbl];
#pragma unroll
        for (int e2 = 0; e2 < 4; ++e2) {
          int jb = kbl * 32 + 8 * e2 + 4 * hi;
          int byte = (q * 128 + jb * 2) ^ ((q & 7) << 4);
          union { unsigned u[2]; s16x4 v; } w;
          w.u[0] = cvtpk(sv[e2 * 4 + 0], sv[e2 * 4 + 1]);
          w.u[1] = cvtpk(sv[e2 * 4 + 2], sv[e2 * 4 + 3]);
          *(s16x4*)((char*)Ps[wv] + byte) = w.v;
        }
      }
      __builtin_amdgcn_sched_barrier(0);  // P writes before PV reads
#pragma unroll
      for (int kblk = 0; kblk < 4; ++kblk) {
        bf16x8 pf = ldsfrag(Ps[wv], q, kblk * 2 + hi);
#pragma unroll
        for (int dblk = 0; dblk < 2; ++dblk) {
          bf16x8 vf = ldsfrag(Vs[hp], dblk * 32 + q, kblk * 2 + hi);
          o32[dblk] = MFMA32(pf, vf, o32[dblk]);
        }
      }
      __builtin_amdgcn_sched_barrier(0);  // PV reads before next half's writes
    }
  }

  // epilogue: complete row sums, O*rcp(l) -> (B, N, nh*hd) bf16
  lrun += __shfl_xor(lrun, 32);
#pragma unroll
  for (int e = 0; e < 16; ++e) {
    int qr = (e & 3) + 8 * (e >> 2) + 4 * hi;
    float lv = __builtin_amdgcn_rcpf(__shfl(lrun, qr));
    int i = qt * 128 + wv * 32 + qr;
#pragma unroll
    for (int dblk = 0; dblk < 2; ++dblk) {
      int d = dblk * 32 + q;
      float val = o32[dblk][e] * lv;
      ao[((size_t)b * 1024 + i) * 768 + h * 64 + d] = f2b(val);
    }
  }
}

// ---------------------------------------------------------------- launcher
extern "C" void kernel_launch(void* const* d_in, const int* in_sizes, int n_in,
                              void* d_out, int out_size, void* d_ws, size_t ws_size,
                              hipStream_t stream) {
  const float* x = (const float*)d_in[0];
  const float* qkvw = (const float*)d_in[1];
  const float* projw = (const float*)d_in[2];
  const float* projb = (const float*)d_in[3];
  const float* btab = (const float*)d_in[4];
  float* out = (float*)d_out;
  char* ws = (char*)d_ws;

  // workspace layout (bytes)
  u16* xb = (u16*)(ws);                    // 8192*768 bf16 = 12,582,912 B
  u16* wqkvT = (u16*)(ws + 12582912);      // 2304*768 bf16 =  3,538,944 B
  u16* wprojT = (u16*)(ws + 16121856);     //  768*768 bf16 =  1,179,648 B
  u16* qbuf = (u16*)(ws + 17301504);       // 12,582,912 B
  u16* kbuf = (u16*)(ws + 29884416);       // 12,582,912 B
  u16* vTbuf = (u16*)(ws + 42467328);      // 12,582,912 B
  u16* biasx = (u16*)(ws + 55050240);      // 12*63*32*32*2 = 1,548,288 B
  u16* ao = xb;  // reuse: xb dead after QKV GEMM (stream-serialized)

  cast_x_kernel<<<6144, 256, 0, stream>>>(x, xb, 8192 * 768 / 4);
  transpose_cast<<<dim3(72, 24), 256, 0, stream>>>(qkvw, wqkvT, 768, 2304);
  transpose_cast<<<dim3(24, 24), 256, 0, stream>>>(projw, wprojT, 768, 768);
  gather_bias<<<3024, 256, 0, stream>>>(btab, biasx);

  gemm128<0><<<dim3(18, 64), 256, 0, stream>>>(xb, wqkvT, 768, qbuf, kbuf,
                                               vTbuf, nullptr, nullptr, 0);

  attn_kernel<<<768, 256, 0, stream>>>(qbuf, kbuf, vTbuf, biasx, ao);

  gemm128<1><<<dim3(6, 64), 256, 0, stream>>>(ao, wprojT, 768, nullptr, nullptr,
                                              nullptr, projb, out, 768);
}

// Round 15
// 146.656 us; speedup vs baseline: 1.8118x; 1.0423x over previous
//
#include <hip/hip_runtime.h>

typedef unsigned short u16;
typedef __attribute__((ext_vector_type(8))) short bf16x8;
typedef __attribute__((ext_vector_type(4))) short s16x4;
typedef __attribute__((ext_vector_type(4))) float f32x4;
typedef __attribute__((ext_vector_type(16))) float f32x16;

#define MFMA(a, b, c) __builtin_amdgcn_mfma_f32_16x16x32_bf16(a, b, c, 0, 0, 0)
#define MFMA32(a, b, c) __builtin_amdgcn_mfma_f32_32x32x16_bf16(a, b, c, 0, 0, 0)

// global -> LDS direct copy, 16 B per lane. LDS dest must be wave-uniform base
// (HW adds lane*16). Global source is per-lane.
#define GLDS16(gp, lp)                                                        \
  __builtin_amdgcn_global_load_lds(                                          \
      (__attribute__((address_space(1))) void*)(void*)(gp),                  \
      (__attribute__((address_space(3))) void*)(lp), 16, 0, 0)

__device__ __forceinline__ u16 f2b(float f) {
  union { float f; unsigned u; } x; x.f = f;
  unsigned r = x.u + 0x7fffu + ((x.u >> 16) & 1u);
  return (u16)(r >> 16);
}
__device__ __forceinline__ float b2f(u16 v) {
  union { unsigned u; float f; } x; x.u = ((unsigned)v) << 16;
  return x.f;
}
// pack two f32 -> one u32 of two bf16 (elem0 = a, elem1 = b)
__device__ __forceinline__ unsigned cvtpk(float a, float b) {
  unsigned r;
  asm("v_cvt_pk_bf16_f32 %0, %1, %2" : "=v"(r) : "v"(a), "v"(b));
  return r;
}
// swap a[lanes>=32] with b[lanes<32]: after, a = (lo: a_self, hi: b from
// lane-32), b = (lo: a from lane+32, hi: b_self).
__device__ __forceinline__ void pl32swap(unsigned& a, unsigned& b) {
  asm volatile("v_permlane32_swap_b32 %0, %1" : "+v"(a), "+v"(b));
}

// Stage a [32*NPASS rows][64 cols] bf16 tile into LDS with XOR-swizzled SOURCE
// slots so a swizzled ds_read recovers linear data. (256-thread version.)
template <int NPASS>
__device__ __forceinline__ void stage64(const u16* __restrict__ src, int ld,
                                        u16* lds, int t) {
  int wave = t >> 6;
#pragma unroll
  for (int p = 0; p < NPASS; ++p) {
    int row = p * 32 + (t >> 3);
    int ss = (t & 7) ^ (row & 7);
    const u16* g = src + row * ld + ss * 8;
    GLDS16(g, lds + (p * 2048 + wave * 512));
  }
}

// read one MFMA fragment (8 consecutive bf16) at [row][slot*8], swizzle-corrected
__device__ __forceinline__ bf16x8 ldsfrag(const u16* base, int row, int slot) {
  int byte = row * 128 + (((slot) ^ (row & 7)) << 4);
  return *(const bf16x8*)((const char*)base + byte);
}

// ---------------------------------------------------------------- prep kernels
__global__ void cast_x_kernel(const float* __restrict__ in, u16* __restrict__ out,
                              int n4) {
  int i = blockIdx.x * blockDim.x + threadIdx.x;
  if (i < n4) {
    float4 v = ((const float4*)in)[i];
    ushort4 o;
    o.x = f2b(v.x); o.y = f2b(v.y); o.z = f2b(v.z); o.w = f2b(v.w);
    ((ushort4*)out)[i] = o;
  }
}

// out[(c, r)] = bf16(in[(r, c)]); in is (R, Ccols) fp32 row-major.
__global__ void transpose_cast(const float* __restrict__ in, u16* __restrict__ out,
                               int R, int Ccols) {
  __shared__ u16 tile[32][33];
  int c0 = blockIdx.x * 32, r0 = blockIdx.y * 32;
  int tx = threadIdx.x & 31, ty = threadIdx.x >> 5;
#pragma unroll
  for (int rr = ty; rr < 32; rr += 8)
    tile[rr][tx] = f2b(in[(size_t)(r0 + rr) * Ccols + c0 + tx]);
  __syncthreads();
#pragma unroll
  for (int rr = ty; rr < 32; rr += 8)
    out[(size_t)(c0 + rr) * R + r0 + tx] = tile[tx][rr];
}

// bias_table (65025,12) fp32 -> lane-order-expanded bf16 biasx[h][dy][q][p]:
// p = e + 16*hi encodes the 32x32 MFMA C/D row j31 = (e&3)+8*(e>>2)+4*hi;
// value = bias[dy][q + 31 - j31] * log2(e). 12*63*32*32 u16 = 1.5 MB.
__global__ void gather_bias(const float* __restrict__ btab, u16* __restrict__ out) {
  int i = blockIdx.x * 256 + threadIdx.x;  // [0, 12*63*32*32)
  int p = i & 31, q = (i >> 5) & 31, dy = (i >> 10) % 63, h = i / (63 * 1024);
  int hi = p >> 4, e = p & 15;
  int j31 = (e & 3) + 8 * (e >> 2) + 4 * hi;
  int dx = q + 31 - j31;  // always in [0, 62]
  out[i] = f2b(btab[(dy * 63 + dx) * 12 + h] * 1.44269504f);
}

// ---------------------------------------------------------------- GEMM 128x128
// C = A(M,K) @ BT(N,K)^T, bf16 inputs, fp32 accum.
template <int EPI>
__global__ __launch_bounds__(256, 3) void gemm128(
    const u16* __restrict__ A, const u16* __restrict__ BT, int K,
    u16* __restrict__ qo, u16* __restrict__ ko, u16* __restrict__ vo,
    const float* __restrict__ pb, float* __restrict__ out, int Nld) {
  __shared__ __align__(16) u16 As[128 * 64];
  __shared__ __align__(16) u16 Bs[128 * 64];
  const int t = threadIdx.x;
  const int wave = t >> 6, lane = t & 63;
  const int wr = wave >> 1, wc = wave & 1;
  const int tileRow = blockIdx.y * 128, tileCol = blockIdx.x * 128;
  const u16* Ab = A + (size_t)tileRow * K;
  const u16* Bb = BT + (size_t)tileCol * K;

  f32x4 acc[4][4] = {};
  for (int k0 = 0; k0 < K; k0 += 64) {
    __syncthreads();
    stage64<4>(Ab + k0, K, As, t);
    stage64<4>(Bb + k0, K, Bs, t);
    __syncthreads();
#pragma unroll
    for (int kk = 0; kk < 2; ++kk) {
      bf16x8 af[4], bfr[4];
#pragma unroll
      for (int m = 0; m < 4; ++m)
        af[m] = ldsfrag(As, wr * 64 + m * 16 + (lane & 15), kk * 4 + (lane >> 4));
#pragma unroll
      for (int n = 0; n < 4; ++n)
        bfr[n] = ldsfrag(Bs, wc * 64 + n * 16 + (lane & 15), kk * 4 + (lane >> 4));
#pragma unroll
      for (int m = 0; m < 4; ++m)
#pragma unroll
        for (int n = 0; n < 4; ++n)
          acc[m][n] = MFMA(af[m], bfr[n], acc[m][n]);
    }
  }

#pragma unroll
  for (int m = 0; m < 4; ++m) {
#pragma unroll
    for (int n = 0; n < 4; ++n) {
#pragma unroll
      for (int r = 0; r < 4; ++r) {
        int row = tileRow + wr * 64 + m * 16 + (lane >> 4) * 4 + r;
        int col = tileCol + wc * 64 + n * 16 + (lane & 15);
        float val = acc[m][n][r];
        if (EPI == 0) {
          int which = col / 768;
          int c = col - which * 768;
          int hh = c >> 6, d = c & 63;
          int bb = row >> 10, nn = row & 1023;
          size_t bhnd = ((size_t)(bb * 12 + hh) * 1024 + nn) * 64 + d;
          if (which == 0)
            qo[bhnd] = f2b(val * 0.18033688f);  // 0.125 * log2(e)
          else if (which == 1)
            ko[bhnd] = f2b(val);
          else
            vo[((size_t)(bb * 12 + hh) * 64 + d) * 1024 + nn] = f2b(val);
        } else {
          out[(size_t)row * Nld + col] = val + pb[col];
        }
      }
    }
  }
}

// ---------------------------------------------------------------- attention
// 32x32x16 MFMA, 4 waves x 32 q-rows (QBLK=128), KVBLK=128, bias from the
// lane-order global table. P NEVER touches LDS: after exp2, each kb's 16
// P-values are cvt_pk'd to 8 u32 and exchanged with the hi-partner lane via
// v_permlane32_swap_b32 -- [w0..w3] and [w4..w7] are then exact PV A-frags
// for BOTH hi halves. LDS holds only K/V tiles (32 KB).
// grid: 768 flat (XCD-chunked: one batch per XCD); block: 256 (4 waves).
__global__ __launch_bounds__(256, 3) void attn_kernel(
    const u16* __restrict__ qm, const u16* __restrict__ kmat,
    const u16* __restrict__ vT, const u16* __restrict__ biasx,
    u16* __restrict__ ao) {
  __shared__ __align__(16) u16 Ks[2][64 * 64];
  __shared__ __align__(16) u16 Vs[2][64 * 64];

  const int t = threadIdx.x;
  const int wv = t >> 6, lane = t & 63;
  const int hi = lane >> 5, q = lane & 31;
  // XCD-chunked swizzle: id%8 = XCD, one batch (96 blocks) per XCD.
  const int id = blockIdx.x;
  const int sw = (id & 7) * 96 + (id >> 3);
  const int qt = sw & 7, h = (sw >> 3) % 12, b = sw / 96;
  const int bh = b * 12 + h;

  const u16* kb0 = kmat + (size_t)bh * 1024 * 64;
  const u16* vb0 = vT + (size_t)bh * 64 * 1024;
  // per-lane bias base: biasx[h][*][q][hi*16]
  const u16* bx0 = biasx + (((size_t)h * 63) * 32 + q) * 32 + hi * 16;

  // Q fragments (q pre-scaled by 0.125*log2e). B-operand: col = q-row = lane&31,
  // k = (lane>>5)*8 + i within d-block of 16.
  const u16* qb = qm + ((size_t)bh * 1024 + qt * 128 + wv * 32) * 64;
  bf16x8 qf[4];
#pragma unroll
  for (int dblk = 0; dblk < 4; ++dblk)
    qf[dblk] = *(const bf16x8*)(qb + q * 64 + dblk * 16 + hi * 8);

  f32x16 o32[2] = {};                 // O[32q x 64d]: 2 d-blocks of 32
  float mrun = -1e30f, lrun = 0.f;    // per-lane partial sum (64 of 128 keys)

  const int ldy0 = wv + qt * 4 + 31;  // ldy = ldy0 - kt8*4 - kb, in [0,62]

  for (int kt8 = 0; kt8 < 8; ++kt8) {
    __syncthreads();  // all waves done reading K/V (prev round)
    stage64<2>(kb0 + kt8 * 8192, 64, Ks[0], t);
    stage64<2>(kb0 + kt8 * 8192 + 4096, 64, Ks[1], t);
    stage64<2>(vb0 + kt8 * 128, 1024, Vs[0], t);
    stage64<2>(vb0 + kt8 * 128 + 64, 1024, Vs[1], t);

    // bias fragments from global (L2-hit, coalesced); overlap with DMA
    bf16x8 bb[4][2];
#pragma unroll
    for (int kb = 0; kb < 4; ++kb) {
      const u16* bp = bx0 + (size_t)(ldy0 - kt8 * 4 - kb) * 1024;
      bb[kb][0] = *(const bf16x8*)(bp);
      bb[kb][1] = *(const bf16x8*)(bp + 8);
    }
    __syncthreads();  // 128-key tile landed

    // S^T = K @ Q^T: s4[kb] covers keys kb*32 + (e&3)+8*(e>>2)+4*hi, q-col = q
    f32x16 s4[4] = {};
#pragma unroll
    for (int kb = 0; kb < 4; ++kb) {
      const u16* Kc = Ks[kb >> 1];
      int krow = (kb & 1) * 32 + q;
#pragma unroll
      for (int dblk = 0; dblk < 4; ++dblk) {
        bf16x8 kf = ldsfrag(Kc, krow, dblk * 2 + hi);
        s4[kb] = MFMA32(kf, qf[dblk], s4[kb]);
      }
    }

    // + relative position bias (exp2-domain), from registers
#pragma unroll
    for (int kb = 0; kb < 4; ++kb)
#pragma unroll
      for (int e = 0; e < 16; ++e)
        s4[kb][e] += b2f((u16)(e < 8 ? bb[kb][0][e] : bb[kb][1][e - 8]));

    // LOCAL max (63 fmax, no shuffles); __any is ballot-equivalent to row test
    float mx = -1e30f;
#pragma unroll
    for (int kb = 0; kb < 4; ++kb)
#pragma unroll
      for (int e = 0; e < 16; ++e) mx = fmaxf(mx, s4[kb][e]);

    if (__any(mx > mrun + 11.5f)) {  // rare path
      float mf = fmaxf(mx, __shfl_xor(mx, 32));
      float mn = fmaxf(mrun, mf);
      float al = __builtin_amdgcn_exp2f(mrun - mn);
      mrun = mn;
      lrun *= al;
#pragma unroll
      for (int e = 0; e < 16; ++e) {
        int qr = (e & 3) + 8 * (e >> 2) + 4 * hi;
        float ar = __shfl(al, qr);
        o32[0][e] *= ar;
        o32[1][e] *= ar;
      }
    }

    // exp2 + per-lane partial sum
#pragma unroll
    for (int kb = 0; kb < 4; ++kb)
#pragma unroll
      for (int e = 0; e < 16; ++e) {
        float p = __builtin_amdgcn_exp2f(s4[kb][e] - mrun);
        s4[kb][e] = p;
        lrun += p;
      }

    // P -> bf16 A-frags IN REGISTERS: cvt_pk pairs + permlane32_swap with the
    // hi-partner lane. After the 4 swaps, [w0..w3] = A-frag for keys
    // kb*32 + 0..15 and [w4..w7] = keys kb*32 + 16..31, for both hi halves.
#pragma unroll
    for (int kb = 0; kb < 4; ++kb) {
      const f32x16& sv = s4[kb];
      unsigned w[8];
#pragma unroll
      for (int m = 0; m < 8; ++m) w[m] = cvtpk(sv[2 * m], sv[2 * m + 1]);
      pl32swap(w[0], w[2]);
      pl32swap(w[1], w[3]);
      pl32swap(w[4], w[6]);
      pl32swap(w[5], w[7]);
      const u16* Vc = Vs[kb >> 1];
#pragma unroll
      for (int kk16 = 0; kk16 < 2; ++kk16) {
        union { unsigned u[4]; bf16x8 v; } pa;
        pa.u[0] = w[kk16 * 4 + 0];
        pa.u[1] = w[kk16 * 4 + 1];
        pa.u[2] = w[kk16 * 4 + 2];
        pa.u[3] = w[kk16 * 4 + 3];
        int slot16 = (kb & 1) * 2 + kk16;
#pragma unroll
        for (int dblk = 0; dblk < 2; ++dblk) {
          bf16x8 vf = ldsfrag(Vc, dblk * 32 + q, slot16 * 2 + hi);
          o32[dblk] = MFMA32(pa.v, vf, o32[dblk]);
        }
      }
    }
  }

  // epilogue: complete row sums, O*rcp(l) -> (B, N, nh*hd) bf16
  lrun += __shfl_xor(lrun, 32);
#pragma unroll
  for (int e = 0; e < 16; ++e) {
    int qr = (e & 3) + 8 * (e >> 2) + 4 * hi;
    float lv = __builtin_amdgcn_rcpf(__shfl(lrun, qr));
    int i = qt * 128 + wv * 32 + qr;
#pragma unroll
    for (int dblk = 0; dblk < 2; ++dblk) {
      int d = dblk * 32 + q;
      float val = o32[dblk][e] * lv;
      ao[((size_t)b * 1024 + i) * 768 + h * 64 + d] = f2b(val);
    }
  }
}

// ---------------------------------------------------------------- launcher
extern "C" void kernel_launch(void* const* d_in, const int* in_sizes, int n_in,
                              void* d_out, int out_size, void* d_ws, size_t ws_size,
                              hipStream_t stream) {
  const float* x = (const float*)d_in[0];
  const float* qkvw = (const float*)d_in[1];
  const float* projw = (const float*)d_in[2];
  const float* projb = (const float*)d_in[3];
  const float* btab = (const float*)d_in[4];
  float* out = (float*)d_out;
  char* ws = (char*)d_ws;

  // workspace layout (bytes)
  u16* xb = (u16*)(ws);                    // 8192*768 bf16 = 12,582,912 B
  u16* wqkvT = (u16*)(ws + 12582912);      // 2304*768 bf16 =  3,538,944 B
  u16* wprojT = (u16*)(ws + 16121856);     //  768*768 bf16 =  1,179,648 B
  u16* qbuf = (u16*)(ws + 17301504);       // 12,582,912 B
  u16* kbuf = (u16*)(ws + 29884416);       // 12,582,912 B
  u16* vTbuf = (u16*)(ws + 42467328);      // 12,582,912 B
  u16* biasx = (u16*)(ws + 55050240);      // 12*63*32*32*2 = 1,548,288 B
  u16* ao = xb;  // reuse: xb dead after QKV GEMM (stream-serialized)

  cast_x_kernel<<<6144, 256, 0, stream>>>(x, xb, 8192 * 768 / 4);
  transpose_cast<<<dim3(72, 24), 256, 0, stream>>>(qkvw, wqkvT, 768, 2304);
  transpose_cast<<<dim3(24, 24), 256, 0, stream>>>(projw, wprojT, 768, 768);
  gather_bias<<<3024, 256, 0, stream>>>(btab, biasx);

  gemm128<0><<<dim3(18, 64), 256, 0, stream>>>(xb, wqkvT, 768, qbuf, kbuf,
                                               vTbuf, nullptr, nullptr, 0);

  attn_kernel<<<768, 256, 0, stream>>>(qbuf, kbuf, vTbuf, biasx, ao);

  gemm128<1><<<dim3(6, 64), 256, 0, stream>>>(ao, wprojT, 768, nullptr, nullptr,
                                              nullptr, projb, out, 768);
}

// Round 16
// 125.913 us; speedup vs baseline: 2.1103x; 1.1647x over previous
//
#include <hip/hip_runtime.h>

typedef unsigned short u16;
typedef __attribute__((ext_vector_type(8))) short bf16x8;
typedef __attribute__((ext_vector_type(4))) short s16x4;
typedef __attribute__((ext_vector_type(4))) float f32x4;
typedef __attribute__((ext_vector_type(16))) float f32x16;

#define MFMA(a, b, c) __builtin_amdgcn_mfma_f32_16x16x32_bf16(a, b, c, 0, 0, 0)
#define MFMA32(a, b, c) __builtin_amdgcn_mfma_f32_32x32x16_bf16(a, b, c, 0, 0, 0)

// global -> LDS direct copy, 16 B per lane. LDS dest must be wave-uniform base
// (HW adds lane*16). Global source is per-lane.
#define GLDS16(gp, lp)                                                        \
  __builtin_amdgcn_global_load_lds(                                          \
      (__attribute__((address_space(1))) void*)(void*)(gp),                  \
      (__attribute__((address_space(3))) void*)(lp), 16, 0, 0)

__device__ __forceinline__ u16 f2b(float f) {
  union { float f; unsigned u; } x; x.f = f;
  unsigned r = x.u + 0x7fffu + ((x.u >> 16) & 1u);
  return (u16)(r >> 16);
}
__device__ __forceinline__ float b2f(u16 v) {
  union { unsigned u; float f; } x; x.u = ((unsigned)v) << 16;
  return x.f;
}
// pack two f32 -> one u32 of two bf16 (elem0 = a, elem1 = b)
__device__ __forceinline__ unsigned cvtpk(float a, float b) {
  unsigned r;
  asm("v_cvt_pk_bf16_f32 %0, %1, %2" : "=v"(r) : "v"(a), "v"(b));
  return r;
}
// swap a[lanes>=32] with b[lanes<32]: after, a = (lo: a_self, hi: b from
// lane-32), b = (lo: a from lane+32, hi: b_self).
__device__ __forceinline__ void pl32swap(unsigned& a, unsigned& b) {
  asm volatile("v_permlane32_swap_b32 %0, %1" : "+v"(a), "+v"(b));
}

// Stage a [32*NPASS rows][64 cols] bf16 tile into LDS with XOR-swizzled SOURCE
// slots so a swizzled ds_read recovers linear data. (256-thread version.)
template <int NPASS>
__device__ __forceinline__ void stage64(const u16* __restrict__ src, int ld,
                                        u16* lds, int t) {
  int wave = t >> 6;
#pragma unroll
  for (int p = 0; p < NPASS; ++p) {
    int row = p * 32 + (t >> 3);
    int ss = (t & 7) ^ (row & 7);
    const u16* g = src + row * ld + ss * 8;
    GLDS16(g, lds + (p * 2048 + wave * 512));
  }
}

// read one MFMA fragment (8 consecutive bf16) at [row][slot*8], swizzle-corrected
__device__ __forceinline__ bf16x8 ldsfrag(const u16* base, int row, int slot) {
  int byte = row * 128 + (((slot) ^ (row & 7)) << 4);
  return *(const bf16x8*)((const char*)base + byte);
}

// ---------------------------------------------------------------- prep kernels
__global__ void cast_x_kernel(const float* __restrict__ in, u16* __restrict__ out,
                              int n4) {
  int i = blockIdx.x * blockDim.x + threadIdx.x;
  if (i < n4) {
    float4 v = ((const float4*)in)[i];
    ushort4 o;
    o.x = f2b(v.x); o.y = f2b(v.y); o.z = f2b(v.z); o.w = f2b(v.w);
    ((ushort4*)out)[i] = o;
  }
}

// out[(c, r)] = bf16(in[(r, c)]); in is (R, Ccols) fp32 row-major.
__global__ void transpose_cast(const float* __restrict__ in, u16* __restrict__ out,
                               int R, int Ccols) {
  __shared__ u16 tile[32][33];
  int c0 = blockIdx.x * 32, r0 = blockIdx.y * 32;
  int tx = threadIdx.x & 31, ty = threadIdx.x >> 5;
#pragma unroll
  for (int rr = ty; rr < 32; rr += 8)
    tile[rr][tx] = f2b(in[(size_t)(r0 + rr) * Ccols + c0 + tx]);
  __syncthreads();
#pragma unroll
  for (int rr = ty; rr < 32; rr += 8)
    out[(size_t)(c0 + rr) * R + r0 + tx] = tile[tx][rr];
}

// bias_table (65025,12) fp32 -> lane-order-expanded bf16 biasx[h][dy][q][p]:
// p = e + 16*hi encodes the 32x32 MFMA C/D row j31 = (e&3)+8*(e>>2)+4*hi;
// value = bias[dy][q + 31 - j31] * log2(e). 12*63*32*32 u16 = 1.5 MB.
__global__ void gather_bias(const float* __restrict__ btab, u16* __restrict__ out) {
  int i = blockIdx.x * 256 + threadIdx.x;  // [0, 12*63*32*32)
  int p = i & 31, q = (i >> 5) & 31, dy = (i >> 10) % 63, h = i / (63 * 1024);
  int hi = p >> 4, e = p & 15;
  int j31 = (e & 3) + 8 * (e >> 2) + 4 * hi;
  int dx = q + 31 - j31;  // always in [0, 62]
  out[i] = f2b(btab[(dy * 63 + dx) * 12 + h] * 1.44269504f);
}

// ---------------------------------------------------------------- GEMM 128x128
// C = A(M,K) @ BT(N,K)^T, bf16 inputs, fp32 accum. 1-D grid, XCD-chunked
// swizzle (nwg % 8 == 0). NT = tiles along N.
template <int EPI>
__global__ __launch_bounds__(256, 3) void gemm128(
    const u16* __restrict__ A, const u16* __restrict__ BT, int K, int NT,
    u16* __restrict__ qo, u16* __restrict__ ko, u16* __restrict__ vo,
    const float* __restrict__ pb, float* __restrict__ out, int Nld) {
  __shared__ __align__(16) u16 As[128 * 64];
  __shared__ __align__(16) u16 Bs[128 * 64];
  const int t = threadIdx.x;
  const int wave = t >> 6, lane = t & 63;
  const int wr = wave >> 1, wc = wave & 1;
  // XCD-chunked swizzle: id%8 = XCD, contiguous row-panel chunk per XCD.
  const int cpx = gridDim.x >> 3;
  const int id = blockIdx.x;
  const int sw = (id & 7) * cpx + (id >> 3);
  const int trow = sw / NT;
  const int tileRow = trow * 128, tileCol = (sw - trow * NT) * 128;
  const u16* Ab = A + (size_t)tileRow * K;
  const u16* Bb = BT + (size_t)tileCol * K;

  f32x4 acc[4][4] = {};
  for (int k0 = 0; k0 < K; k0 += 64) {
    __syncthreads();
    stage64<4>(Ab + k0, K, As, t);
    stage64<4>(Bb + k0, K, Bs, t);
    __syncthreads();
#pragma unroll
    for (int kk = 0; kk < 2; ++kk) {
      bf16x8 af[4], bfr[4];
#pragma unroll
      for (int m = 0; m < 4; ++m)
        af[m] = ldsfrag(As, wr * 64 + m * 16 + (lane & 15), kk * 4 + (lane >> 4));
#pragma unroll
      for (int n = 0; n < 4; ++n)
        bfr[n] = ldsfrag(Bs, wc * 64 + n * 16 + (lane & 15), kk * 4 + (lane >> 4));
#pragma unroll
      for (int m = 0; m < 4; ++m)
#pragma unroll
        for (int n = 0; n < 4; ++n)
          acc[m][n] = MFMA(af[m], bfr[n], acc[m][n]);
    }
  }

  if (EPI == 0) {
    // which segment (q/k/v) is BLOCK-UNIFORM: 768 = 6 x 128-tiles.
    const int which = tileCol / 768;
    const int cb = tileCol - which * 768;
    if (which == 0) {  // q, scaled by 0.125*log2e, (b,h,n,d) layout
#pragma unroll
      for (int m = 0; m < 4; ++m)
#pragma unroll
        for (int n = 0; n < 4; ++n) {
          int c = cb + wc * 64 + n * 16 + (lane & 15);
          int hh = c >> 6, d = c & 63;
#pragma unroll
          for (int r = 0; r < 4; ++r) {
            int row = tileRow + wr * 64 + m * 16 + (lane >> 4) * 4 + r;
            int bb = row >> 10, nn = row & 1023;
            qo[((size_t)(bb * 12 + hh) * 1024 + nn) * 64 + d] =
                f2b(acc[m][n][r] * 0.18033688f);
          }
        }
    } else if (which == 1) {  // k, (b,h,n,d) layout
#pragma unroll
      for (int m = 0; m < 4; ++m)
#pragma unroll
        for (int n = 0; n < 4; ++n) {
          int c = cb + wc * 64 + n * 16 + (lane & 15);
          int hh = c >> 6, d = c & 63;
#pragma unroll
          for (int r = 0; r < 4; ++r) {
            int row = tileRow + wr * 64 + m * 16 + (lane >> 4) * 4 + r;
            int bb = row >> 10, nn = row & 1023;
            ko[((size_t)(bb * 12 + hh) * 1024 + nn) * 64 + d] =
                f2b(acc[m][n][r]);
          }
        }
    } else {  // v -> vT (b,h,d,n): r-values are nn-contiguous -> b64 stores
#pragma unroll
      for (int m = 0; m < 4; ++m)
#pragma unroll
        for (int n = 0; n < 4; ++n) {
          int c = cb + wc * 64 + n * 16 + (lane & 15);
          int hh = c >> 6, d = c & 63;
          int rowb = tileRow + wr * 64 + m * 16 + (lane >> 4) * 4;
          int bb = rowb >> 10, nn = rowb & 1023;
          union { unsigned u[2]; s16x4 v; } w;
          w.u[0] = cvtpk(acc[m][n][0], acc[m][n][1]);
          w.u[1] = cvtpk(acc[m][n][2], acc[m][n][3]);
          *(s16x4*)(vo + (((size_t)(bb * 12 + hh) * 64 + d) * 1024 + nn)) = w.v;
        }
    }
  } else {
#pragma unroll
    for (int m = 0; m < 4; ++m)
#pragma unroll
      for (int n = 0; n < 4; ++n) {
        int col = tileCol + wc * 64 + n * 16 + (lane & 15);
#pragma unroll
        for (int r = 0; r < 4; ++r) {
          int row = tileRow + wr * 64 + m * 16 + (lane >> 4) * 4 + r;
          out[(size_t)row * Nld + col] = acc[m][n][r] + pb[col];
        }
      }
  }
}

// ---------------------------------------------------------------- attention
// 32x32x16 MFMA, 4 waves x 32 q-rows (QBLK=128), KVBLK=128, bias from the
// lane-order global table. P NEVER touches LDS: after exp2, each kb's 16
// P-values are cvt_pk'd to 8 u32 and exchanged with the hi-partner lane via
// v_permlane32_swap_b32 -- [w0..w3] and [w4..w7] are then exact PV A-frags
// for BOTH hi halves. LDS holds only K/V tiles (32 KB).
// grid: 768 flat (XCD-chunked: one batch per XCD); block: 256 (4 waves).
__global__ __launch_bounds__(256, 3) void attn_kernel(
    const u16* __restrict__ qm, const u16* __restrict__ kmat,
    const u16* __restrict__ vT, const u16* __restrict__ biasx,
    u16* __restrict__ ao) {
  __shared__ __align__(16) u16 Ks[2][64 * 64];
  __shared__ __align__(16) u16 Vs[2][64 * 64];

  const int t = threadIdx.x;
  const int wv = t >> 6, lane = t & 63;
  const int hi = lane >> 5, q = lane & 31;
  // XCD-chunked swizzle: id%8 = XCD, one batch (96 blocks) per XCD.
  const int id = blockIdx.x;
  const int sw = (id & 7) * 96 + (id >> 3);
  const int qt = sw & 7, h = (sw >> 3) % 12, b = sw / 96;
  const int bh = b * 12 + h;

  const u16* kb0 = kmat + (size_t)bh * 1024 * 64;
  const u16* vb0 = vT + (size_t)bh * 64 * 1024;
  // per-lane bias base: biasx[h][*][q][hi*16]
  const u16* bx0 = biasx + (((size_t)h * 63) * 32 + q) * 32 + hi * 16;

  // Q fragments (q pre-scaled by 0.125*log2e). B-operand: col = q-row = lane&31,
  // k = (lane>>5)*8 + i within d-block of 16.
  const u16* qb = qm + ((size_t)bh * 1024 + qt * 128 + wv * 32) * 64;
  bf16x8 qf[4];
#pragma unroll
  for (int dblk = 0; dblk < 4; ++dblk)
    qf[dblk] = *(const bf16x8*)(qb + q * 64 + dblk * 16 + hi * 8);

  f32x16 o32[2] = {};                 // O[32q x 64d]: 2 d-blocks of 32
  float mrun = -1e30f, lrun = 0.f;    // per-lane partial sum (64 of 128 keys)

  const int ldy0 = wv + qt * 4 + 31;  // ldy = ldy0 - kt8*4 - kb, in [0,62]

  for (int kt8 = 0; kt8 < 8; ++kt8) {
    __syncthreads();  // all waves done reading K/V (prev round)
    stage64<2>(kb0 + kt8 * 8192, 64, Ks[0], t);
    stage64<2>(kb0 + kt8 * 8192 + 4096, 64, Ks[1], t);
    stage64<2>(vb0 + kt8 * 128, 1024, Vs[0], t);
    stage64<2>(vb0 + kt8 * 128 + 64, 1024, Vs[1], t);

    // bias fragments from global (L2-hit, coalesced); overlap with DMA
    bf16x8 bb[4][2];
#pragma unroll
    for (int kb = 0; kb < 4; ++kb) {
      const u16* bp = bx0 + (size_t)(ldy0 - kt8 * 4 - kb) * 1024;
      bb[kb][0] = *(const bf16x8*)(bp);
      bb[kb][1] = *(const bf16x8*)(bp + 8);
    }
    __syncthreads();  // 128-key tile landed

    // S^T = K @ Q^T: s4[kb] covers keys kb*32 + (e&3)+8*(e>>2)+4*hi, q-col = q
    f32x16 s4[4] = {};
#pragma unroll
    for (int kb = 0; kb < 4; ++kb) {
      const u16* Kc = Ks[kb >> 1];
      int krow = (kb & 1) * 32 + q;
#pragma unroll
      for (int dblk = 0; dblk < 4; ++dblk) {
        bf16x8 kf = ldsfrag(Kc, krow, dblk * 2 + hi);
        s4[kb] = MFMA32(kf, qf[dblk], s4[kb]);
      }
    }

    // + relative position bias (exp2-domain), from registers
#pragma unroll
    for (int kb = 0; kb < 4; ++kb)
#pragma unroll
      for (int e = 0; e < 16; ++e)
        s4[kb][e] += b2f((u16)(e < 8 ? bb[kb][0][e] : bb[kb][1][e - 8]));

    // LOCAL max (63 fmax, no shuffles); __any is ballot-equivalent to row test
    float mx = -1e30f;
#pragma unroll
    for (int kb = 0; kb < 4; ++kb)
#pragma unroll
      for (int e = 0; e < 16; ++e) mx = fmaxf(mx, s4[kb][e]);

    if (__any(mx > mrun + 11.5f)) {  // rare path
      float mf = fmaxf(mx, __shfl_xor(mx, 32));
      float mn = fmaxf(mrun, mf);
      float al = __builtin_amdgcn_exp2f(mrun - mn);
      mrun = mn;
      lrun *= al;
#pragma unroll
      for (int e = 0; e < 16; ++e) {
        int qr = (e & 3) + 8 * (e >> 2) + 4 * hi;
        float ar = __shfl(al, qr);
        o32[0][e] *= ar;
        o32[1][e] *= ar;
      }
    }

    // exp2 + per-lane partial sum
#pragma unroll
    for (int kb = 0; kb < 4; ++kb)
#pragma unroll
      for (int e = 0; e < 16; ++e) {
        float p = __builtin_amdgcn_exp2f(s4[kb][e] - mrun);
        s4[kb][e] = p;
        lrun += p;
      }

    // P -> bf16 A-frags IN REGISTERS: cvt_pk pairs + permlane32_swap with the
    // hi-partner lane. After the 4 swaps, [w0..w3] = A-frag for keys
    // kb*32 + 0..15 and [w4..w7] = keys kb*32 + 16..31, for both hi halves.
#pragma unroll
    for (int kb = 0; kb < 4; ++kb) {
      const f32x16& sv = s4[kb];
      unsigned w[8];
#pragma unroll
      for (int m = 0; m < 8; ++m) w[m] = cvtpk(sv[2 * m], sv[2 * m + 1]);
      pl32swap(w[0], w[2]);
      pl32swap(w[1], w[3]);
      pl32swap(w[4], w[6]);
      pl32swap(w[5], w[7]);
      const u16* Vc = Vs[kb >> 1];
#pragma unroll
      for (int kk16 = 0; kk16 < 2; ++kk16) {
        union { unsigned u[4]; bf16x8 v; } pa;
        pa.u[0] = w[kk16 * 4 + 0];
        pa.u[1] = w[kk16 * 4 + 1];
        pa.u[2] = w[kk16 * 4 + 2];
        pa.u[3] = w[kk16 * 4 + 3];
        int slot16 = (kb & 1) * 2 + kk16;
#pragma unroll
        for (int dblk = 0; dblk < 2; ++dblk) {
          bf16x8 vf = ldsfrag(Vc, dblk * 32 + q, slot16 * 2 + hi);
          o32[dblk] = MFMA32(pa.v, vf, o32[dblk]);
        }
      }
    }
  }

  // epilogue: complete row sums, O*rcp(l) -> (B, N, nh*hd) bf16
  lrun += __shfl_xor(lrun, 32);
#pragma unroll
  for (int e = 0; e < 16; ++e) {
    int qr = (e & 3) + 8 * (e >> 2) + 4 * hi;
    float lv = __builtin_amdgcn_rcpf(__shfl(lrun, qr));
    int i = qt * 128 + wv * 32 + qr;
#pragma unroll
    for (int dblk = 0; dblk < 2; ++dblk) {
      int d = dblk * 32 + q;
      float val = o32[dblk][e] * lv;
      ao[((size_t)b * 1024 + i) * 768 + h * 64 + d] = f2b(val);
    }
  }
}

// ---------------------------------------------------------------- launcher
extern "C" void kernel_launch(void* const* d_in, const int* in_sizes, int n_in,
                              void* d_out, int out_size, void* d_ws, size_t ws_size,
                              hipStream_t stream) {
  const float* x = (const float*)d_in[0];
  const float* qkvw = (const float*)d_in[1];
  const float* projw = (const float*)d_in[2];
  const float* projb = (const float*)d_in[3];
  const float* btab = (const float*)d_in[4];
  float* out = (float*)d_out;
  char* ws = (char*)d_ws;

  // workspace layout (bytes)
  u16* xb = (u16*)(ws);                    // 8192*768 bf16 = 12,582,912 B
  u16* wqkvT = (u16*)(ws + 12582912);      // 2304*768 bf16 =  3,538,944 B
  u16* wprojT = (u16*)(ws + 16121856);     //  768*768 bf16 =  1,179,648 B
  u16* qbuf = (u16*)(ws + 17301504);       // 12,582,912 B
  u16* kbuf = (u16*)(ws + 29884416);       // 12,582,912 B
  u16* vTbuf = (u16*)(ws + 42467328);      // 12,582,912 B
  u16* biasx = (u16*)(ws + 55050240);      // 12*63*32*32*2 = 1,548,288 B
  u16* ao = xb;  // reuse: xb dead after QKV GEMM (stream-serialized)

  cast_x_kernel<<<6144, 256, 0, stream>>>(x, xb, 8192 * 768 / 4);
  transpose_cast<<<dim3(72, 24), 256, 0, stream>>>(qkvw, wqkvT, 768, 2304);
  transpose_cast<<<dim3(24, 24), 256, 0, stream>>>(projw, wprojT, 768, 768);
  gather_bias<<<3024, 256, 0, stream>>>(btab, biasx);

  // 18 col-tiles x 64 row-tiles = 1152 blocks (1152 % 8 == 0)
  gemm128<0><<<1152, 256, 0, stream>>>(xb, wqkvT, 768, 18, qbuf, kbuf,
                                       vTbuf, nullptr, nullptr, 0);

  attn_kernel<<<768, 256, 0, stream>>>(qbuf, kbuf, vTbuf, biasx, ao);

  // 6 col-tiles x 64 row-tiles = 384 blocks (384 % 8 == 0)
  gemm128<1><<<384, 256, 0, stream>>>(ao, wprojT, 768, 6, nullptr, nullptr,
                                      nullptr, projb, out, 768);
}